// Round 2
// baseline (3411.823 us; speedup 1.0000x reference)
//
#include <hip/hip_runtime.h>
#include <hip/hip_bf16.h>
#include <math.h>

#define CDIV(a,b) (((a)+(b)-1)/(b))

constexpr int N_   = 80000;
constexpr int NC_  = 8000;
constexpr int G_   = 16;
constexpr int C_   = 5;
constexpr int CFGF = 18;
constexpr int OPF  = 140;
constexpr int OPE  = 32;
constexpr int H_   = 32;
constexpr int NF_  = OPF + OPE;   // 172
constexpr int CROW = C_ * CFGF;   // 90
constexpr int XROW = C_ * H_;     // 160
constexpr int DGC  = CFGF + H_;   // 50
constexpr int YROW = C_ * DGC;    // 250
constexpr float ALPHA_ = 0.2f;

__device__ __forceinline__ float lrelu(float v) { return v >= 0.0f ? v : ALPHA_ * v; }

// nfw[n][h] = pre_b1[h] + sum_f op_feats[n][f]*w1[18+f][h] + sum_e emb[op_ids[n]][e]*w1[158+e][h]
__global__ void k_nfw(const float* __restrict__ opf, const int* __restrict__ op_ids,
                      const float* __restrict__ emb, const float* __restrict__ w1,
                      const float* __restrict__ b1, float* __restrict__ nfw) {
    __shared__ float sw[NF_ * H_];   // rows 18..189 of pre_w1, 22 KB
    for (int i = threadIdx.x; i < NF_ * H_; i += blockDim.x) sw[i] = w1[CFGF * H_ + i];
    __syncthreads();
    int t = blockIdx.x * blockDim.x + threadIdx.x;
    int n = t >> 5, h = t & 31;
    if (n >= N_) return;
    float acc = b1[h];
    const float* f = opf + (size_t)n * OPF;
    #pragma unroll 4
    for (int i = 0; i < OPF; ++i) acc = fmaf(f[i], sw[i * H_ + h], acc);
    const float* e = emb + (size_t)op_ids[n] * OPE;
    #pragma unroll 4
    for (int i = 0; i < OPE; ++i) acc = fmaf(e[i], sw[(OPF + i) * H_ + h], acc);
    nfw[(size_t)n * H_ + h] = acc;
}

// cfg[cdst[i]][c][f] += 100 * config_feats[csrc[i]][c][f]
__global__ void k_cfg_scatter(const float* __restrict__ cf, const int* __restrict__ csrc,
                              const int* __restrict__ cdst, float* __restrict__ cfg) {
    int t = blockIdx.x * blockDim.x + threadIdx.x;
    if (t >= NC_ * CROW) return;
    int i = t / CROW, j = t - i * CROW;
    int s = csrc[i], d = cdst[i];
    atomicAdd(&cfg[(size_t)d * CROW + j], 100.0f * cf[(size_t)s * CROW + j]);
}

__global__ void k_deg(const int* __restrict__ src, const int* __restrict__ dst,
                      int E, int* __restrict__ deg) {
    int e = blockIdx.x * blockDim.x + threadIdx.x;
    if (e >= E) return;
    atomicAdd(&deg[src[e]], 1);
    atomicAdd(&deg[dst[e]], 1);
}

__global__ void k_inv(const int* __restrict__ deg, float* __restrict__ inv) {
    int n = blockIdx.x * blockDim.x + threadIdx.x;
    if (n >= N_) return;
    inv[n] = 1.0f / sqrtf((float)(deg[n] + 1));   // +1 self loop
}

// x[r] = lrelu( lrelu(cfg_part + nfw[n]) @ w2 + b2 ),  r = n*C + c
__global__ void k_pre(const float* __restrict__ cfg, const float* __restrict__ nfw,
                      const float* __restrict__ w1, const float* __restrict__ w2,
                      const float* __restrict__ b2, float* __restrict__ x) {
    __shared__ float sw1[CFGF * H_];
    __shared__ float sw2[H_ * H_];
    __shared__ float sb2[H_];
    for (int i = threadIdx.x; i < CFGF * H_; i += blockDim.x) sw1[i] = w1[i];
    for (int i = threadIdx.x; i < H_ * H_; i += blockDim.x) sw2[i] = w2[i];
    if (threadIdx.x < H_) sb2[threadIdx.x] = b2[threadIdx.x];
    __syncthreads();
    int r = blockIdx.x * blockDim.x + threadIdx.x;
    if (r >= N_ * C_) return;
    int n = r / C_;
    float cv[CFGF];
    const float* cg = cfg + (size_t)r * CFGF;
    #pragma unroll
    for (int f = 0; f < CFGF; ++f) cv[f] = cg[f];
    const float* nw = nfw + (size_t)n * H_;
    float h1[H_];
    #pragma unroll
    for (int h = 0; h < H_; ++h) {
        float a = nw[h];
        #pragma unroll
        for (int f = 0; f < CFGF; ++f) a = fmaf(cv[f], sw1[f * H_ + h], a);
        h1[h] = lrelu(a);
    }
    float* xo = x + (size_t)r * H_;
    #pragma unroll
    for (int h = 0; h < H_; ++h) {
        float a = sb2[h];
        #pragma unroll
        for (int k = 0; k < H_; ++k) a = fmaf(h1[k], sw2[k * H_ + h], a);
        xo[h] = lrelu(a);
    }
}

// y[n][c][j] = inv[n] * (j<18 ? cfg[n][c][j] : x[n][c][j-18])   (self-loop term)
__global__ void k_yinit(const float* __restrict__ cfg, const float* __restrict__ x,
                        const float* __restrict__ inv, float* __restrict__ y) {
    long long t = (long long)blockIdx.x * blockDim.x + threadIdx.x;
    if (t >= (long long)N_ * YROW) return;
    int n = (int)(t / YROW);
    int q = (int)(t - (long long)n * YROW);
    int c = q / DGC, j = q - c * DGC;
    float v = (j < CFGF) ? cfg[(size_t)n * CROW + c * CFGF + j]
                         : x[(size_t)n * XROW + c * H_ + (j - CFGF)];
    y[t] = v * inv[n];
}

// one wave per directed edge: y[d][q] += inv[s] * concat(cfg,x)[s][q]
__global__ void k_scatter(const int* __restrict__ src, const int* __restrict__ dst, int E,
                          const float* __restrict__ cfg, const float* __restrict__ x,
                          const float* __restrict__ inv, float* __restrict__ y) {
    int wid = (blockIdx.x * blockDim.x + threadIdx.x) >> 6;
    int lane = threadIdx.x & 63;
    if (wid >= 2 * E) return;
    int e = wid >> 1;
    int s, d;
    if (wid & 1) { s = dst[e]; d = src[e]; } else { s = src[e]; d = dst[e]; }
    float invs = inv[s];
    const float* cg = cfg + (size_t)s * CROW;
    const float* xs = x + (size_t)s * XROW;
    float* yd = y + (size_t)d * YROW;
    for (int q = lane; q < YROW; q += 64) {
        int c = q / DGC, j = q - c * DGC;
        float v = (j < CFGF) ? cg[c * CFGF + j] : xs[c * H_ + (j - CFGF)];
        atomicAdd(&yd[q], v * invs);
    }
}

// x[r] += lrelu( lrelu((y[r]*inv[n]) @ w1 + b1) @ w2 + b2 )
__global__ void k_gcmlp(const float* __restrict__ y, const float* __restrict__ inv,
                        const float* __restrict__ w1, const float* __restrict__ b1,
                        const float* __restrict__ w2, const float* __restrict__ b2,
                        float* __restrict__ x) {
    __shared__ float sw1[DGC * H_];
    __shared__ float sw2[H_ * H_];
    __shared__ float sb1[H_];
    __shared__ float sb2[H_];
    for (int i = threadIdx.x; i < DGC * H_; i += blockDim.x) sw1[i] = w1[i];
    for (int i = threadIdx.x; i < H_ * H_; i += blockDim.x) sw2[i] = w2[i];
    if (threadIdx.x < H_) { sb1[threadIdx.x] = b1[threadIdx.x]; sb2[threadIdx.x] = b2[threadIdx.x]; }
    __syncthreads();
    int r = blockIdx.x * blockDim.x + threadIdx.x;
    if (r >= N_ * C_) return;
    int n = r / C_;
    float iv = inv[n];
    float yr[DGC];
    const float* yp = y + (size_t)r * DGC;
    #pragma unroll
    for (int f = 0; f < DGC; ++f) yr[f] = yp[f] * iv;
    float h1[H_];
    #pragma unroll
    for (int h = 0; h < H_; ++h) {
        float a = sb1[h];
        #pragma unroll
        for (int f = 0; f < DGC; ++f) a = fmaf(yr[f], sw1[f * H_ + h], a);
        h1[h] = lrelu(a);
    }
    float* xo = x + (size_t)r * H_;
    #pragma unroll
    for (int h = 0; h < H_; ++h) {
        float a = sb2[h];
        #pragma unroll
        for (int k = 0; k < H_; ++k) a = fmaf(h1[k], sw2[k * H_ + h], a);
        xo[h] = xo[h] + lrelu(a);
    }
}

// op_sum over groups (selected-combined x) + counts. blockDim = 160 (= C*H)
__global__ void k_opsum(const float* __restrict__ xf, const float* __restrict__ xb,
                        const int* __restrict__ sel, const int* __restrict__ op_gid,
                        float* __restrict__ osum, float* __restrict__ cnt) {
    __shared__ float ls[G_ * XROW];
    __shared__ float lc[G_];
    for (int i = threadIdx.x; i < G_ * XROW; i += blockDim.x) ls[i] = 0.0f;
    if (threadIdx.x < G_) lc[threadIdx.x] = 0.0f;
    __syncthreads();
    int j = threadIdx.x;   // element within (C,H) row
    int base = blockIdx.x * 512;
    for (int i = 0; i < 512; ++i) {
        int n = base + i;
        if (n >= N_) break;
        int g = op_gid[n];
        const float* xr = sel[n] ? xb : xf;
        ls[g * XROW + j] += xr[(size_t)n * XROW + j];
        if (j == 0) lc[g] += 1.0f;
    }
    __syncthreads();
    for (int i = threadIdx.x; i < G_ * XROW; i += blockDim.x) atomicAdd(&osum[i], ls[i]);
    if (threadIdx.x < G_) atomicAdd(&cnt[threadIdx.x], lc[threadIdx.x]);
}

// cfg_sum[g] += x[cdst[e]] where g = cfg_gid[csrc[e]]. blockDim = 160
__global__ void k_cfgsum(const float* __restrict__ xf, const float* __restrict__ xb,
                         const int* __restrict__ sel, const int* __restrict__ csrc,
                         const int* __restrict__ cdst, const int* __restrict__ cfg_gid,
                         float* __restrict__ csum) {
    __shared__ float ls[G_ * XROW];
    for (int i = threadIdx.x; i < G_ * XROW; i += blockDim.x) ls[i] = 0.0f;
    __syncthreads();
    int j = threadIdx.x;
    int base = blockIdx.x * 256;
    for (int i = 0; i < 256; ++i) {
        int e = base + i;
        if (e >= NC_) break;
        int g = cfg_gid[csrc[e]];
        int n = cdst[e];
        const float* xr = sel[n] ? xb : xf;
        ls[g * XROW + j] += xr[(size_t)n * XROW + j];
    }
    __syncthreads();
    for (int i = threadIdx.x; i < G_ * XROW; i += blockDim.x) atomicAdd(&csum[i], ls[i]);
}

// feats = [op_mean, l2norm(op_sum), l2norm(cfg_sum)]; out = lrelu(feats@pw1)@pw2
__global__ void k_final(const float* __restrict__ osum, const float* __restrict__ csum,
                        const float* __restrict__ cnt, const float* __restrict__ pw1,
                        const float* __restrict__ pw2, float* __restrict__ out) {
    __shared__ float sw1[3 * H_ * H_];
    __shared__ float sw2[H_];
    for (int i = threadIdx.x; i < 3 * H_ * H_; i += blockDim.x) sw1[i] = pw1[i];
    if (threadIdx.x < H_) sw2[threadIdx.x] = pw2[threadIdx.x];
    __syncthreads();
    int t = threadIdx.x;
    if (t >= G_ * C_) return;
    int g = t / C_;
    const float* os = osum + (size_t)t * H_;
    const float* cs = csum + (size_t)t * H_;
    float icnt = 1.0f / cnt[g];
    float a0[H_], a1[H_], a2[H_];
    float s1 = 0.0f, s2 = 0.0f;
    #pragma unroll
    for (int h = 0; h < H_; ++h) {
        float v1 = os[h], v2 = cs[h];
        a0[h] = v1 * icnt;
        a1[h] = v1; s1 = fmaf(v1, v1, s1);
        a2[h] = v2; s2 = fmaf(v2, v2, s2);
    }
    float r1 = 1.0f / sqrtf(fmaxf(s1, 1e-12f));
    float r2 = 1.0f / sqrtf(fmaxf(s2, 1e-12f));
    #pragma unroll
    for (int h = 0; h < H_; ++h) { a1[h] *= r1; a2[h] *= r2; }
    float o = 0.0f;
    #pragma unroll
    for (int h = 0; h < H_; ++h) {
        float a = 0.0f;
        #pragma unroll
        for (int k = 0; k < H_; ++k) a = fmaf(a0[k], sw1[k * H_ + h], a);
        #pragma unroll
        for (int k = 0; k < H_; ++k) a = fmaf(a1[k], sw1[(H_ + k) * H_ + h], a);
        #pragma unroll
        for (int k = 0; k < H_; ++k) a = fmaf(a2[k], sw1[(2 * H_ + k) * H_ + h], a);
        o = fmaf(lrelu(a), sw2[h], o);
    }
    out[t] = o;
}

extern "C" void kernel_launch(void* const* d_in, const int* in_sizes, int n_in,
                              void* d_out, int out_size, void* d_ws, size_t ws_size,
                              hipStream_t stream) {
    const float* op_feats     = (const float*)d_in[0];
    const float* config_feats = (const float*)d_in[1];
    const int*   op_ids       = (const int*)d_in[2];
    const int*   selected     = (const int*)d_in[3];
    const int*   feed_src     = (const int*)d_in[4];
    const int*   feed_dst     = (const int*)d_in[5];
    const int*   sfeed_src    = (const int*)d_in[6];
    const int*   sfeed_dst    = (const int*)d_in[7];
    const int*   config_src   = (const int*)d_in[8];
    const int*   config_dst   = (const int*)d_in[9];
    const int*   sconfig_src  = (const int*)d_in[10];
    const int*   sconfig_dst  = (const int*)d_in[11];
    const int*   op_gid       = (const int*)d_in[12];
    const int*   cfg_gid      = (const int*)d_in[13];
    const float* emb          = (const float*)d_in[14];
    const float* pre_w1       = (const float*)d_in[15];
    const float* pre_b1       = (const float*)d_in[16];
    const float* pre_w2       = (const float*)d_in[17];
    const float* pre_b2       = (const float*)d_in[18];
    const float* gc_w1[2]     = {(const float*)d_in[19], (const float*)d_in[23]};
    const float* gc_b1[2]     = {(const float*)d_in[20], (const float*)d_in[24]};
    const float* gc_w2[2]     = {(const float*)d_in[21], (const float*)d_in[25]};
    const float* gc_b2[2]     = {(const float*)d_in[22], (const float*)d_in[26]};
    const float* post_w1      = (const float*)d_in[27];
    const float* post_w2      = (const float*)d_in[28];

    char* ws = (char*)d_ws;
    size_t off = 0;
    auto alloc = [&](size_t bytes) { void* p = ws + off; off += (bytes + 255) & ~(size_t)255; return p; };
    float* nfw  = (float*)alloc((size_t)N_ * H_ * 4);     // 10.24 MB
    float* cfg  = (float*)alloc((size_t)N_ * CROW * 4);   // 28.8 MB
    float* inv  = (float*)alloc((size_t)N_ * 4);
    int*   deg  = (int*)alloc((size_t)N_ * 4);
    float* xf   = (float*)alloc((size_t)N_ * XROW * 4);   // 51.2 MB
    float* xb   = (float*)alloc((size_t)N_ * XROW * 4);   // 51.2 MB
    float* y    = (float*)alloc((size_t)N_ * YROW * 4);   // 80 MB
    float* osum = (float*)alloc((size_t)G_ * XROW * 4);
    float* csum = (float*)alloc((size_t)G_ * XROW * 4);
    float* cntb = (float*)alloc((size_t)G_ * 4);

    k_nfw<<<CDIV(N_ * H_, 256), 256, 0, stream>>>(op_feats, op_ids, emb, pre_w1, pre_b1, nfw);

    for (int fwd = 0; fwd < 2; ++fwd) {
        const int* esrc = fwd ? sfeed_src : feed_src;
        const int* edst = fwd ? sfeed_dst : feed_dst;
        int Ecur = fwd ? in_sizes[6] : in_sizes[4];
        const int* csrc = fwd ? sconfig_src : config_src;
        const int* cdst = fwd ? sconfig_dst : config_dst;
        float* x = fwd ? xb : xf;

        hipMemsetAsync(cfg, 0, (size_t)N_ * CROW * 4, stream);
        hipMemsetAsync(deg, 0, (size_t)N_ * 4, stream);
        k_cfg_scatter<<<CDIV(NC_ * CROW, 256), 256, 0, stream>>>(config_feats, csrc, cdst, cfg);
        k_deg<<<CDIV(Ecur, 256), 256, 0, stream>>>(esrc, edst, Ecur, deg);
        k_inv<<<CDIV(N_, 256), 256, 0, stream>>>(deg, inv);
        k_pre<<<CDIV(N_ * C_, 256), 256, 0, stream>>>(cfg, nfw, pre_w1, pre_w2, pre_b2, x);

        for (int l = 0; l < 2; ++l) {
            k_yinit<<<CDIV(N_ * YROW, 256), 256, 0, stream>>>(cfg, x, inv, y);
            k_scatter<<<CDIV(2 * Ecur * 64, 256), 256, 0, stream>>>(esrc, edst, Ecur, cfg, x, inv, y);
            k_gcmlp<<<CDIV(N_ * C_, 256), 256, 0, stream>>>(y, inv, gc_w1[l], gc_b1[l], gc_w2[l], gc_b2[l], x);
        }
    }

    hipMemsetAsync(osum, 0, (size_t)G_ * XROW * 4, stream);
    hipMemsetAsync(csum, 0, (size_t)G_ * XROW * 4, stream);
    hipMemsetAsync(cntb, 0, (size_t)G_ * 4, stream);
    k_opsum<<<CDIV(N_, 512), 160, 0, stream>>>(xf, xb, selected, op_gid, osum, cntb);
    k_cfgsum<<<CDIV(NC_, 256), 160, 0, stream>>>(xf, xb, selected, config_src, config_dst, cfg_gid, csum);
    k_final<<<1, 128, 0, stream>>>(osum, csum, cntb, post_w1, post_w2, (float*)d_out);
}

// Round 3
// 1834.746 us; speedup vs baseline: 1.8596x; 1.8596x over previous
//
#include <hip/hip_runtime.h>
#include <hip/hip_bf16.h>
#include <math.h>

#define CDIV(a,b) (((a)+(b)-1)/(b))

constexpr int N_   = 80000;
constexpr int NC_  = 8000;
constexpr int G_   = 16;
constexpr int C_   = 5;
constexpr int CFGF = 18;
constexpr int OPF  = 140;
constexpr int OPE  = 32;
constexpr int H_   = 32;
constexpr int NF_  = OPF + OPE;   // 172
constexpr int CROW = C_ * CFGF;   // 90
constexpr int XROW = C_ * H_;     // 160
constexpr int TR   = 64;          // rows per MLP tile
constexpr float ALPHA_ = 0.2f;

__device__ __forceinline__ float lrelu(float v) { return v >= 0.0f ? v : ALPHA_ * v; }

// nfw[n][h] = pre_b1[h] + op_feats[n] @ w1[18:158] + emb[op_ids[n]] @ w1[158:190]
__global__ void k_nfw(const float* __restrict__ opf, const int* __restrict__ op_ids,
                      const float* __restrict__ emb, const float* __restrict__ w1,
                      const float* __restrict__ b1, float* __restrict__ nfw) {
    __shared__ float sw[NF_ * H_];
    for (int i = threadIdx.x; i < NF_ * H_; i += blockDim.x) sw[i] = w1[CFGF * H_ + i];
    __syncthreads();
    int t = blockIdx.x * blockDim.x + threadIdx.x;
    int n = t >> 5, h = t & 31;
    if (n >= N_) return;
    float acc = b1[h];
    const float* f = opf + (size_t)n * OPF;
    #pragma unroll 4
    for (int i = 0; i < OPF; ++i) acc = fmaf(f[i], sw[i * H_ + h], acc);
    const float* e = emb + (size_t)op_ids[n] * OPE;
    #pragma unroll 4
    for (int i = 0; i < OPE; ++i) acc = fmaf(e[i], sw[(OPF + i) * H_ + h], acc);
    nfw[(size_t)n * H_ + h] = acc;
}

// cfg[cdst[i]][c][f] += 100 * config_feats[csrc[i]][c][f]
__global__ void k_cfg_scatter(const float* __restrict__ cf, const int* __restrict__ csrc,
                              const int* __restrict__ cdst, float* __restrict__ cfg) {
    int t = blockIdx.x * blockDim.x + threadIdx.x;
    if (t >= NC_ * CROW) return;
    int i = t / CROW, j = t - i * CROW;
    int s = csrc[i], d = cdst[i];
    atomicAdd(&cfg[(size_t)d * CROW + j], 100.0f * cf[(size_t)s * CROW + j]);
}

__global__ void k_deg(const int* __restrict__ src, const int* __restrict__ dst,
                      int E, int* __restrict__ deg) {
    int e = blockIdx.x * blockDim.x + threadIdx.x;
    if (e >= E) return;
    atomicAdd(&deg[src[e]], 1);
    atomicAdd(&deg[dst[e]], 1);
}

__global__ void k_inv(const int* __restrict__ deg, float* __restrict__ inv) {
    int n = blockIdx.x * blockDim.x + threadIdx.x;
    if (n >= N_) return;
    inv[n] = 1.0f / sqrtf((float)(deg[n] + 1));   // +1 self loop
}

// csum init: csum[r][f] = cfg[r][f] * inv[r / C]   (self-loop contribution)
__global__ void k_csum_init(const float* __restrict__ cfg, const float* __restrict__ inv,
                            float* __restrict__ csum) {
    int t = blockIdx.x * blockDim.x + threadIdx.x;
    if (t >= N_ * CROW) return;
    csum[t] = cfg[t] * inv[t / CROW];
}

// wave per directed edge: csum[d][q] += inv[s] * cfg[s][q], q in [0,90)
__global__ void k_csum_scatter(const int* __restrict__ src, const int* __restrict__ dst, int E,
                               const float* __restrict__ cfg, const float* __restrict__ inv,
                               float* __restrict__ csum) {
    int wid = (blockIdx.x * blockDim.x + threadIdx.x) >> 6;
    int lane = threadIdx.x & 63;
    if (wid >= 2 * E) return;
    int e = wid >> 1;
    int s, d;
    if (wid & 1) { s = dst[e]; d = src[e]; } else { s = src[e]; d = dst[e]; }
    float invs = inv[s];
    const float* cg = cfg + (size_t)s * CROW;
    float* cd = csum + (size_t)d * CROW;
    for (int q = lane; q < CROW; q += 64) atomicAdd(&cd[q], cg[q] * invs);
}

// wave per directed edge: xs[d][q] += inv[s] * x[s][q], q in [0,160)
__global__ void k_xs_scatter(const int* __restrict__ src, const int* __restrict__ dst, int E,
                             const float* __restrict__ x, const float* __restrict__ inv,
                             float* __restrict__ xs) {
    int wid = (blockIdx.x * blockDim.x + threadIdx.x) >> 6;
    int lane = threadIdx.x & 63;
    if (wid >= 2 * E) return;
    int e = wid >> 1;
    int s, d;
    if (wid & 1) { s = dst[e]; d = src[e]; } else { s = src[e]; d = dst[e]; }
    float invs = inv[s];
    const float* xsrc = x + (size_t)s * XROW;
    float* xd = xs + (size_t)d * XROW;
    for (int q = lane; q < XROW; q += 64) atomicAdd(&xd[q], xsrc[q] * invs);
}

// tiled pre-MLP: x[r] = lrelu(lrelu(cfg[r]@w1c + nfw[n]) @ w2 + b2); xs[r] = x[r]*inv[n]
__global__ void k_pre(const float* __restrict__ cfg, const float* __restrict__ nfw,
                      const float* __restrict__ inv,
                      const float* __restrict__ w1, const float* __restrict__ w2,
                      const float* __restrict__ b2, float* __restrict__ x,
                      float* __restrict__ xs) {
    __shared__ float scfg[TR * CFGF];
    __shared__ float snfw[TR * H_];
    __shared__ float sh1[TR * H_];
    __shared__ float sw1[CFGF * H_];
    __shared__ float sw2[H_ * H_];
    __shared__ float sb2[H_];
    __shared__ float sinv[TR];
    int base = blockIdx.x * TR;
    for (int i = threadIdx.x; i < CFGF * H_; i += blockDim.x) sw1[i] = w1[i];
    for (int i = threadIdx.x; i < H_ * H_; i += blockDim.x) sw2[i] = w2[i];
    if (threadIdx.x < H_) sb2[threadIdx.x] = b2[threadIdx.x];
    for (int i = threadIdx.x; i < TR * CFGF; i += blockDim.x) scfg[i] = cfg[(size_t)base * CFGF + i];
    for (int i = threadIdx.x; i < TR * H_; i += blockDim.x)
        snfw[i] = nfw[(size_t)((base + (i >> 5)) / C_) * H_ + (i & 31)];
    if (threadIdx.x < TR) sinv[threadIdx.x] = inv[(base + threadIdx.x) / C_];
    __syncthreads();
    int h = threadIdx.x & 31, rs = threadIdx.x >> 5;
    #pragma unroll
    for (int p = 0; p < 8; ++p) {
        int row = rs * 8 + p;
        float a = snfw[row * H_ + h];
        #pragma unroll
        for (int f = 0; f < CFGF; ++f) a = fmaf(scfg[row * CFGF + f], sw1[f * H_ + h], a);
        sh1[row * H_ + h] = lrelu(a);
    }
    __syncthreads();
    #pragma unroll
    for (int p = 0; p < 8; ++p) {
        int row = rs * 8 + p;
        float a = sb2[h];
        #pragma unroll
        for (int k = 0; k < H_; ++k) a = fmaf(sh1[row * H_ + k], sw2[k * H_ + h], a);
        float v = lrelu(a);
        size_t o = (size_t)(base + row) * H_ + h;
        x[o] = v;
        xs[o] = v * sinv[row];
    }
}

// tiled GC MLP: t1 = csum[r]@w1[0:18] + xs[r]@w1[18:50];
// x[r] += lrelu(lrelu(b1 + inv*t1) @ w2 + b2); optionally xs[r] = xnew*inv (next layer)
__global__ void k_gcmlp(const float* __restrict__ csum, const float* __restrict__ xsin,
                        const float* __restrict__ inv,
                        const float* __restrict__ w1, const float* __restrict__ b1,
                        const float* __restrict__ w2, const float* __restrict__ b2,
                        float* __restrict__ x, float* __restrict__ xs_next, int write_xs) {
    __shared__ float scs[TR * CFGF];
    __shared__ float sxs[TR * H_];
    __shared__ float sh1[TR * H_];
    __shared__ float sw1[(CFGF + H_) * H_];
    __shared__ float sw2[H_ * H_];
    __shared__ float sb1[H_];
    __shared__ float sb2[H_];
    __shared__ float sinv[TR];
    int base = blockIdx.x * TR;
    for (int i = threadIdx.x; i < (CFGF + H_) * H_; i += blockDim.x) sw1[i] = w1[i];
    for (int i = threadIdx.x; i < H_ * H_; i += blockDim.x) sw2[i] = w2[i];
    if (threadIdx.x < H_) { sb1[threadIdx.x] = b1[threadIdx.x]; sb2[threadIdx.x] = b2[threadIdx.x]; }
    for (int i = threadIdx.x; i < TR * CFGF; i += blockDim.x) scs[i] = csum[(size_t)base * CFGF + i];
    for (int i = threadIdx.x; i < TR * H_; i += blockDim.x) sxs[i] = xsin[(size_t)base * H_ + i];
    if (threadIdx.x < TR) sinv[threadIdx.x] = inv[(base + threadIdx.x) / C_];
    __syncthreads();
    int h = threadIdx.x & 31, rs = threadIdx.x >> 5;
    #pragma unroll
    for (int p = 0; p < 8; ++p) {
        int row = rs * 8 + p;
        float a = 0.0f;
        #pragma unroll
        for (int f = 0; f < CFGF; ++f) a = fmaf(scs[row * CFGF + f], sw1[f * H_ + h], a);
        #pragma unroll
        for (int k = 0; k < H_; ++k) a = fmaf(sxs[row * H_ + k], sw1[(CFGF + k) * H_ + h], a);
        sh1[row * H_ + h] = lrelu(fmaf(sinv[row], a, sb1[h]));
    }
    __syncthreads();
    #pragma unroll
    for (int p = 0; p < 8; ++p) {
        int row = rs * 8 + p;
        float a = sb2[h];
        #pragma unroll
        for (int k = 0; k < H_; ++k) a = fmaf(sh1[row * H_ + k], sw2[k * H_ + h], a);
        size_t o = (size_t)(base + row) * H_ + h;
        float nx = x[o] + lrelu(a);
        x[o] = nx;
        if (write_xs) xs_next[o] = nx * sinv[row];
    }
}

// op_sum over groups (selected-combined x) + counts. blockDim = 160 (= C*H)
__global__ void k_opsum(const float* __restrict__ xf, const float* __restrict__ xb,
                        const int* __restrict__ sel, const int* __restrict__ op_gid,
                        float* __restrict__ osum, float* __restrict__ cnt) {
    __shared__ float ls[G_ * XROW];
    __shared__ float lc[G_];
    for (int i = threadIdx.x; i < G_ * XROW; i += blockDim.x) ls[i] = 0.0f;
    if (threadIdx.x < G_) lc[threadIdx.x] = 0.0f;
    __syncthreads();
    int j = threadIdx.x;
    int base = blockIdx.x * 512;
    for (int i = 0; i < 512; ++i) {
        int n = base + i;
        if (n >= N_) break;
        int g = op_gid[n];
        const float* xr = sel[n] ? xb : xf;
        ls[g * XROW + j] += xr[(size_t)n * XROW + j];
        if (j == 0) lc[g] += 1.0f;
    }
    __syncthreads();
    for (int i = threadIdx.x; i < G_ * XROW; i += blockDim.x) atomicAdd(&osum[i], ls[i]);
    if (threadIdx.x < G_) atomicAdd(&cnt[threadIdx.x], lc[threadIdx.x]);
}

// cfg_sum[g] += x[cdst[e]] where g = cfg_gid[csrc[e]]. blockDim = 160
__global__ void k_cfgsum(const float* __restrict__ xf, const float* __restrict__ xb,
                         const int* __restrict__ sel, const int* __restrict__ csrc,
                         const int* __restrict__ cdst, const int* __restrict__ cfg_gid,
                         float* __restrict__ gsum) {
    __shared__ float ls[G_ * XROW];
    for (int i = threadIdx.x; i < G_ * XROW; i += blockDim.x) ls[i] = 0.0f;
    __syncthreads();
    int j = threadIdx.x;
    int base = blockIdx.x * 256;
    for (int i = 0; i < 256; ++i) {
        int e = base + i;
        if (e >= NC_) break;
        int g = cfg_gid[csrc[e]];
        int n = cdst[e];
        const float* xr = sel[n] ? xb : xf;
        ls[g * XROW + j] += xr[(size_t)n * XROW + j];
    }
    __syncthreads();
    for (int i = threadIdx.x; i < G_ * XROW; i += blockDim.x) atomicAdd(&gsum[i], ls[i]);
}

// feats = [op_mean, l2norm(op_sum), l2norm(cfg_sum)]; out = lrelu(feats@pw1)@pw2
__global__ void k_final(const float* __restrict__ osum, const float* __restrict__ gsum,
                        const float* __restrict__ cnt, const float* __restrict__ pw1,
                        const float* __restrict__ pw2, float* __restrict__ out) {
    __shared__ float sw1[3 * H_ * H_];
    __shared__ float sw2[H_];
    for (int i = threadIdx.x; i < 3 * H_ * H_; i += blockDim.x) sw1[i] = pw1[i];
    if (threadIdx.x < H_) sw2[threadIdx.x] = pw2[threadIdx.x];
    __syncthreads();
    int t = threadIdx.x;
    if (t >= G_ * C_) return;
    int g = t / C_;
    const float* os = osum + (size_t)t * H_;
    const float* cs = gsum + (size_t)t * H_;
    float icnt = 1.0f / cnt[g];
    float a0[H_], a1[H_], a2[H_];
    float s1 = 0.0f, s2 = 0.0f;
    #pragma unroll
    for (int h = 0; h < H_; ++h) {
        float v1 = os[h], v2 = cs[h];
        a0[h] = v1 * icnt;
        a1[h] = v1; s1 = fmaf(v1, v1, s1);
        a2[h] = v2; s2 = fmaf(v2, v2, s2);
    }
    float r1 = 1.0f / sqrtf(fmaxf(s1, 1e-12f));
    float r2 = 1.0f / sqrtf(fmaxf(s2, 1e-12f));
    #pragma unroll
    for (int h = 0; h < H_; ++h) { a1[h] *= r1; a2[h] *= r2; }
    float o = 0.0f;
    #pragma unroll
    for (int h = 0; h < H_; ++h) {
        float a = 0.0f;
        #pragma unroll
        for (int k = 0; k < H_; ++k) a = fmaf(a0[k], sw1[k * H_ + h], a);
        #pragma unroll
        for (int k = 0; k < H_; ++k) a = fmaf(a1[k], sw1[(H_ + k) * H_ + h], a);
        #pragma unroll
        for (int k = 0; k < H_; ++k) a = fmaf(a2[k], sw1[(2 * H_ + k) * H_ + h], a);
        o = fmaf(lrelu(a), sw2[h], o);
    }
    out[t] = o;
}

extern "C" void kernel_launch(void* const* d_in, const int* in_sizes, int n_in,
                              void* d_out, int out_size, void* d_ws, size_t ws_size,
                              hipStream_t stream) {
    const float* op_feats     = (const float*)d_in[0];
    const float* config_feats = (const float*)d_in[1];
    const int*   op_ids       = (const int*)d_in[2];
    const int*   selected     = (const int*)d_in[3];
    const int*   feed_src     = (const int*)d_in[4];
    const int*   feed_dst     = (const int*)d_in[5];
    const int*   sfeed_src    = (const int*)d_in[6];
    const int*   sfeed_dst    = (const int*)d_in[7];
    const int*   config_src   = (const int*)d_in[8];
    const int*   config_dst   = (const int*)d_in[9];
    const int*   sconfig_src  = (const int*)d_in[10];
    const int*   sconfig_dst  = (const int*)d_in[11];
    const int*   op_gid       = (const int*)d_in[12];
    const int*   cfg_gid      = (const int*)d_in[13];
    const float* emb          = (const float*)d_in[14];
    const float* pre_w1       = (const float*)d_in[15];
    const float* pre_b1       = (const float*)d_in[16];
    const float* pre_w2       = (const float*)d_in[17];
    const float* pre_b2       = (const float*)d_in[18];
    const float* gc_w1[2]     = {(const float*)d_in[19], (const float*)d_in[23]};
    const float* gc_b1[2]     = {(const float*)d_in[20], (const float*)d_in[24]};
    const float* gc_w2[2]     = {(const float*)d_in[21], (const float*)d_in[25]};
    const float* gc_b2[2]     = {(const float*)d_in[22], (const float*)d_in[26]};
    const float* post_w1      = (const float*)d_in[27];
    const float* post_w2      = (const float*)d_in[28];

    char* ws = (char*)d_ws;
    size_t off = 0;
    auto alloc = [&](size_t bytes) { void* p = ws + off; off += (bytes + 255) & ~(size_t)255; return p; };
    float* nfw  = (float*)alloc((size_t)N_ * H_ * 4);     // 10.24 MB
    float* cfg  = (float*)alloc((size_t)N_ * CROW * 4);   // 28.8 MB
    float* inv  = (float*)alloc((size_t)N_ * 4);
    int*   deg  = (int*)alloc((size_t)N_ * 4);
    float* xf   = (float*)alloc((size_t)N_ * XROW * 4);   // 51.2 MB
    float* xb   = (float*)alloc((size_t)N_ * XROW * 4);   // 51.2 MB
    float* csum = (float*)alloc((size_t)N_ * CROW * 4);   // 28.8 MB
    float* xs   = (float*)alloc((size_t)N_ * XROW * 4);   // 51.2 MB
    float* osum = (float*)alloc((size_t)G_ * XROW * 4);
    float* gsum = (float*)alloc((size_t)G_ * XROW * 4);
    float* cntb = (float*)alloc((size_t)G_ * 4);

    k_nfw<<<CDIV(N_ * H_, 256), 256, 0, stream>>>(op_feats, op_ids, emb, pre_w1, pre_b1, nfw);

    for (int fwd = 0; fwd < 2; ++fwd) {
        const int* esrc = fwd ? sfeed_src : feed_src;
        const int* edst = fwd ? sfeed_dst : feed_dst;
        int Ecur = fwd ? in_sizes[6] : in_sizes[4];
        const int* csrc = fwd ? sconfig_src : config_src;
        const int* cdst = fwd ? sconfig_dst : config_dst;
        float* x = fwd ? xb : xf;

        hipMemsetAsync(cfg, 0, (size_t)N_ * CROW * 4, stream);
        hipMemsetAsync(deg, 0, (size_t)N_ * 4, stream);
        k_cfg_scatter<<<CDIV(NC_ * CROW, 256), 256, 0, stream>>>(config_feats, csrc, cdst, cfg);
        k_deg<<<CDIV(Ecur, 256), 256, 0, stream>>>(esrc, edst, Ecur, deg);
        k_inv<<<CDIV(N_, 256), 256, 0, stream>>>(deg, inv);
        k_csum_init<<<CDIV(N_ * CROW, 256), 256, 0, stream>>>(cfg, inv, csum);
        k_csum_scatter<<<CDIV(2 * Ecur * 64, 256), 256, 0, stream>>>(esrc, edst, Ecur, cfg, inv, csum);
        k_pre<<<CDIV(N_ * C_, TR), 256, 0, stream>>>(cfg, nfw, inv, pre_w1, pre_w2, pre_b2, x, xs);

        for (int l = 0; l < 2; ++l) {
            k_xs_scatter<<<CDIV(2 * Ecur * 64, 256), 256, 0, stream>>>(esrc, edst, Ecur, x, inv, xs);
            k_gcmlp<<<CDIV(N_ * C_, TR), 256, 0, stream>>>(csum, xs, inv, gc_w1[l], gc_b1[l],
                                                           gc_w2[l], gc_b2[l], x, xs, l == 0);
        }
    }

    hipMemsetAsync(osum, 0, (size_t)G_ * XROW * 4, stream);
    hipMemsetAsync(gsum, 0, (size_t)G_ * XROW * 4, stream);
    hipMemsetAsync(cntb, 0, (size_t)G_ * 4, stream);
    k_opsum<<<CDIV(N_, 512), 160, 0, stream>>>(xf, xb, selected, op_gid, osum, cntb);
    k_cfgsum<<<CDIV(NC_, 256), 160, 0, stream>>>(xf, xb, selected, config_src, config_dst, cfg_gid, gsum);
    k_final<<<1, 128, 0, stream>>>(osum, gsum, cntb, post_w1, post_w2, (float*)d_out);
}

// Round 4
// 1166.335 us; speedup vs baseline: 2.9253x; 1.5731x over previous
//
#include <hip/hip_runtime.h>
#include <hip/hip_bf16.h>
#include <math.h>

#define CDIV(a,b) (((a)+(b)-1)/(b))

constexpr int N_   = 80000;
constexpr int NC_  = 8000;
constexpr int G_   = 16;
constexpr int C_   = 5;
constexpr int CFGF = 18;
constexpr int OPF  = 140;
constexpr int OPE  = 32;
constexpr int H_   = 32;
constexpr int NF_  = OPF + OPE;   // 172
constexpr int CROW = C_ * CFGF;   // 90
constexpr int XROW = C_ * H_;     // 160
constexpr int TR   = 64;          // rows per MLP tile
constexpr float ALPHA_ = 0.2f;

__device__ __forceinline__ float lrelu(float v) { return v >= 0.0f ? v : ALPHA_ * v; }

// nfw[n][h] = pre_b1[h] + op_feats[n] @ w1[18:158] + emb[op_ids[n]] @ w1[158:190]
__global__ void k_nfw(const float* __restrict__ opf, const int* __restrict__ op_ids,
                      const float* __restrict__ emb, const float* __restrict__ w1,
                      const float* __restrict__ b1, float* __restrict__ nfw) {
    __shared__ float sw[NF_ * H_];
    for (int i = threadIdx.x; i < NF_ * H_; i += blockDim.x) sw[i] = w1[CFGF * H_ + i];
    __syncthreads();
    int t = blockIdx.x * blockDim.x + threadIdx.x;
    int n = t >> 5, h = t & 31;
    if (n >= N_) return;
    float acc = b1[h];
    const float* f = opf + (size_t)n * OPF;
    #pragma unroll 4
    for (int i = 0; i < OPF; ++i) acc = fmaf(f[i], sw[i * H_ + h], acc);
    const float* e = emb + (size_t)op_ids[n] * OPE;
    #pragma unroll 4
    for (int i = 0; i < OPE; ++i) acc = fmaf(e[i], sw[(OPF + i) * H_ + h], acc);
    nfw[(size_t)n * H_ + h] = acc;
}

// cfg[cdst[i]][c][f] += 100 * config_feats[csrc[i]][c][f]
__global__ void k_cfg_scatter(const float* __restrict__ cf, const int* __restrict__ csrc,
                              const int* __restrict__ cdst, float* __restrict__ cfg) {
    int t = blockIdx.x * blockDim.x + threadIdx.x;
    if (t >= NC_ * CROW) return;
    int i = t / CROW, j = t - i * CROW;
    int s = csrc[i], d = cdst[i];
    atomicAdd(&cfg[(size_t)d * CROW + j], 100.0f * cf[(size_t)s * CROW + j]);
}

__global__ void k_deg(const int* __restrict__ src, const int* __restrict__ dst,
                      int E, int* __restrict__ deg) {
    int e = blockIdx.x * blockDim.x + threadIdx.x;
    if (e >= E) return;
    atomicAdd(&deg[src[e]], 1);
    atomicAdd(&deg[dst[e]], 1);
}

__global__ void k_inv(const int* __restrict__ deg, float* __restrict__ inv) {
    int n = blockIdx.x * blockDim.x + threadIdx.x;
    if (n >= N_) return;
    inv[n] = 1.0f / sqrtf((float)(deg[n] + 1));   // +1 self loop
}

// ---- CSR build: exclusive scan of deg -> roff, then atomic fill of col ----
__global__ void k_scan1(const int* __restrict__ deg, int* __restrict__ roff, int* __restrict__ aux) {
    __shared__ int s[256];
    int t = threadIdx.x, n = blockIdx.x * 256 + t;
    int v = (n < N_) ? deg[n] : 0;
    s[t] = v; __syncthreads();
    for (int off = 1; off < 256; off <<= 1) {
        int x = (t >= off) ? s[t - off] : 0;
        __syncthreads();
        s[t] += x;
        __syncthreads();
    }
    if (n < N_) roff[n] = s[t] - v;          // exclusive within block
    if (t == 255) aux[blockIdx.x] = s[255];  // block total
}

__global__ void k_scan2(int* __restrict__ aux, int nb) {   // one block, 512 threads
    __shared__ int s[512];
    int t = threadIdx.x;
    int v = (t < nb) ? aux[t] : 0;
    s[t] = v; __syncthreads();
    for (int off = 1; off < 512; off <<= 1) {
        int x = (t >= off) ? s[t - off] : 0;
        __syncthreads();
        s[t] += x;
        __syncthreads();
    }
    if (t < nb) aux[t] = s[t] - v;           // exclusive block offsets
}

__global__ void k_scan3(int* __restrict__ roff, const int* __restrict__ aux,
                        int* __restrict__ cur, int total) {
    int n = blockIdx.x * blockDim.x + threadIdx.x;
    if (n < N_) {
        int r = roff[n] + aux[n >> 8];
        roff[n] = r;
        cur[n] = r;
    }
    if (n == 0) roff[N_] = total;
}

__global__ void k_fill(const int* __restrict__ src, const int* __restrict__ dst, int E,
                       int* __restrict__ cur, int* __restrict__ col) {
    int e = blockIdx.x * blockDim.x + threadIdx.x;
    if (e >= E) return;
    int s = src[e], d = dst[e];
    col[atomicAdd(&cur[d], 1)] = s;
    col[atomicAdd(&cur[s], 1)] = d;
}

// ---- gathers (self + CSR neighbors), no atomics ----
// csum[n][j2] = inv[n]*cfg[n][j2] + sum_s inv[s]*cfg[s][j2]   (float2 lanes, 45/node)
__global__ void k_csum_gather(const float2* __restrict__ cfg2, const float* __restrict__ inv,
                              const int* __restrict__ roff, const int* __restrict__ col,
                              float2* __restrict__ csum2) {
    int t = blockIdx.x * blockDim.x + threadIdx.x;
    if (t >= N_ * 45) return;
    int n = t / 45, j2 = t - n * 45;
    float iv = inv[n];
    float2 a = cfg2[t];
    a.x *= iv; a.y *= iv;
    int p1 = roff[n + 1];
    for (int p = roff[n]; p < p1; ++p) {
        int s = col[p];
        float ivs = inv[s];
        float2 v = cfg2[(size_t)s * 45 + j2];
        a.x = fmaf(v.x, ivs, a.x);
        a.y = fmaf(v.y, ivs, a.y);
    }
    csum2[t] = a;
}

// xs[n][j4] = inv[n]*x[n][j4] + sum_s inv[s]*x[s][j4]   (float4 lanes, 40/node)
__global__ void k_xs_gather(const float4* __restrict__ x4, const float* __restrict__ inv,
                            const int* __restrict__ roff, const int* __restrict__ col,
                            float4* __restrict__ xs4) {
    int t = blockIdx.x * blockDim.x + threadIdx.x;
    if (t >= N_ * 40) return;
    int n = t / 40, j4 = t - n * 40;
    float iv = inv[n];
    float4 a = x4[t];
    a.x *= iv; a.y *= iv; a.z *= iv; a.w *= iv;
    int p1 = roff[n + 1];
    for (int p = roff[n]; p < p1; ++p) {
        int s = col[p];
        float ivs = inv[s];
        float4 v = x4[(size_t)s * 40 + j4];
        a.x = fmaf(v.x, ivs, a.x);
        a.y = fmaf(v.y, ivs, a.y);
        a.z = fmaf(v.z, ivs, a.z);
        a.w = fmaf(v.w, ivs, a.w);
    }
    xs4[t] = a;
}

// tiled pre-MLP: x[r] = lrelu(lrelu(cfg[r]@w1c + nfw[n]) @ w2 + b2)
__global__ void k_pre(const float* __restrict__ cfg, const float* __restrict__ nfw,
                      const float* __restrict__ w1, const float* __restrict__ w2,
                      const float* __restrict__ b2, float* __restrict__ x) {
    __shared__ float scfg[TR * CFGF];
    __shared__ float snfw[TR * H_];
    __shared__ float sh1[TR * H_];
    __shared__ float sw1[CFGF * H_];
    __shared__ float sw2[H_ * H_];
    __shared__ float sb2[H_];
    int base = blockIdx.x * TR;
    for (int i = threadIdx.x; i < CFGF * H_; i += blockDim.x) sw1[i] = w1[i];
    for (int i = threadIdx.x; i < H_ * H_; i += blockDim.x) sw2[i] = w2[i];
    if (threadIdx.x < H_) sb2[threadIdx.x] = b2[threadIdx.x];
    for (int i = threadIdx.x; i < TR * CFGF; i += blockDim.x) scfg[i] = cfg[(size_t)base * CFGF + i];
    for (int i = threadIdx.x; i < TR * H_; i += blockDim.x)
        snfw[i] = nfw[(size_t)((base + (i >> 5)) / C_) * H_ + (i & 31)];
    __syncthreads();
    int h = threadIdx.x & 31, rs = threadIdx.x >> 5;
    #pragma unroll
    for (int p = 0; p < 8; ++p) {
        int row = rs * 8 + p;
        float a = snfw[row * H_ + h];
        #pragma unroll
        for (int f = 0; f < CFGF; ++f) a = fmaf(scfg[row * CFGF + f], sw1[f * H_ + h], a);
        sh1[row * H_ + h] = lrelu(a);
    }
    __syncthreads();
    #pragma unroll
    for (int p = 0; p < 8; ++p) {
        int row = rs * 8 + p;
        float a = sb2[h];
        #pragma unroll
        for (int k = 0; k < H_; ++k) a = fmaf(sh1[row * H_ + k], sw2[k * H_ + h], a);
        x[(size_t)(base + row) * H_ + h] = lrelu(a);
    }
}

// tiled GC MLP: x[r] += lrelu(lrelu(b1 + inv*(csum[r]@w1c + xs[r]@w1x)) @ w2 + b2)
__global__ void k_gcmlp(const float* __restrict__ csum, const float* __restrict__ xsin,
                        const float* __restrict__ inv,
                        const float* __restrict__ w1, const float* __restrict__ b1,
                        const float* __restrict__ w2, const float* __restrict__ b2,
                        float* __restrict__ x) {
    __shared__ float scs[TR * CFGF];
    __shared__ float sxs[TR * H_];
    __shared__ float sh1[TR * H_];
    __shared__ float sw1[(CFGF + H_) * H_];
    __shared__ float sw2[H_ * H_];
    __shared__ float sb1[H_];
    __shared__ float sb2[H_];
    __shared__ float sinv[TR];
    int base = blockIdx.x * TR;
    for (int i = threadIdx.x; i < (CFGF + H_) * H_; i += blockDim.x) sw1[i] = w1[i];
    for (int i = threadIdx.x; i < H_ * H_; i += blockDim.x) sw2[i] = w2[i];
    if (threadIdx.x < H_) { sb1[threadIdx.x] = b1[threadIdx.x]; sb2[threadIdx.x] = b2[threadIdx.x]; }
    for (int i = threadIdx.x; i < TR * CFGF; i += blockDim.x) scs[i] = csum[(size_t)base * CFGF + i];
    for (int i = threadIdx.x; i < TR * H_; i += blockDim.x) sxs[i] = xsin[(size_t)base * H_ + i];
    if (threadIdx.x < TR) sinv[threadIdx.x] = inv[(base + threadIdx.x) / C_];
    __syncthreads();
    int h = threadIdx.x & 31, rs = threadIdx.x >> 5;
    #pragma unroll
    for (int p = 0; p < 8; ++p) {
        int row = rs * 8 + p;
        float a = 0.0f;
        #pragma unroll
        for (int f = 0; f < CFGF; ++f) a = fmaf(scs[row * CFGF + f], sw1[f * H_ + h], a);
        #pragma unroll
        for (int k = 0; k < H_; ++k) a = fmaf(sxs[row * H_ + k], sw1[(CFGF + k) * H_ + h], a);
        sh1[row * H_ + h] = lrelu(fmaf(sinv[row], a, sb1[h]));
    }
    __syncthreads();
    #pragma unroll
    for (int p = 0; p < 8; ++p) {
        int row = rs * 8 + p;
        float a = sb2[h];
        #pragma unroll
        for (int k = 0; k < H_; ++k) a = fmaf(sh1[row * H_ + k], sw2[k * H_ + h], a);
        size_t o = (size_t)(base + row) * H_ + h;
        x[o] = x[o] + lrelu(a);
    }
}

// op_sum: 512 blocks x 256 thr; 6 node-slots x 40 float4-lanes; private LDS per slot
__global__ void k_opsum(const float4* __restrict__ xf4, const float4* __restrict__ xb4,
                        const int* __restrict__ sel, const int* __restrict__ gid,
                        float* __restrict__ osum, float* __restrict__ cnt) {
    __shared__ float4 ls[6 * G_ * 40];
    __shared__ float lc[6 * G_];
    for (int i = threadIdx.x; i < 6 * G_ * 40; i += blockDim.x) ls[i] = make_float4(0.f, 0.f, 0.f, 0.f);
    if (threadIdx.x < 6 * G_) lc[threadIdx.x] = 0.0f;
    __syncthreads();
    int j4 = threadIdx.x % 40, i = threadIdx.x / 40;
    const int NPB = CDIV(N_, 512);
    int start = blockIdx.x * NPB;
    int end = min(start + NPB, N_);
    if (i < 6) {
        for (int n = start + i; n < end; n += 6) {
            int g = gid[n];
            const float4* xr = sel[n] ? xb4 : xf4;
            float4 v = xr[(size_t)n * 40 + j4];
            int o = (i * G_ + g) * 40 + j4;
            float4 c = ls[o];
            c.x += v.x; c.y += v.y; c.z += v.z; c.w += v.w;
            ls[o] = c;
            if (j4 == 0) lc[i * G_ + g] += 1.0f;
        }
    }
    __syncthreads();
    for (int idx = threadIdx.x; idx < G_ * 40; idx += blockDim.x) {
        float4 s = ls[idx];
        #pragma unroll
        for (int q = 1; q < 6; ++q) {
            float4 v = ls[q * G_ * 40 + idx];
            s.x += v.x; s.y += v.y; s.z += v.z; s.w += v.w;
        }
        int g = idx / 40, j = idx - g * 40;
        float* o = osum + (size_t)g * XROW + j * 4;
        atomicAdd(o + 0, s.x); atomicAdd(o + 1, s.y);
        atomicAdd(o + 2, s.z); atomicAdd(o + 3, s.w);
    }
    if (threadIdx.x < G_) {
        float c = 0.0f;
        #pragma unroll
        for (int q = 0; q < 6; ++q) c += lc[q * G_ + threadIdx.x];
        atomicAdd(&cnt[threadIdx.x], c);
    }
}

// cfg_sum: 64 blocks x 256 thr, same 6x40 structure over NC edges
__global__ void k_cfgsum(const float4* __restrict__ xf4, const float4* __restrict__ xb4,
                         const int* __restrict__ sel, const int* __restrict__ csrc,
                         const int* __restrict__ cdst, const int* __restrict__ cfg_gid,
                         float* __restrict__ gsum) {
    __shared__ float4 ls[6 * G_ * 40];
    for (int i = threadIdx.x; i < 6 * G_ * 40; i += blockDim.x) ls[i] = make_float4(0.f, 0.f, 0.f, 0.f);
    __syncthreads();
    int j4 = threadIdx.x % 40, i = threadIdx.x / 40;
    const int EPB = CDIV(NC_, 64);
    int start = blockIdx.x * EPB;
    int end = min(start + EPB, NC_);
    if (i < 6) {
        for (int e = start + i; e < end; e += 6) {
            int g = cfg_gid[csrc[e]];
            int n = cdst[e];
            const float4* xr = sel[n] ? xb4 : xf4;
            float4 v = xr[(size_t)n * 40 + j4];
            int o = (i * G_ + g) * 40 + j4;
            float4 c = ls[o];
            c.x += v.x; c.y += v.y; c.z += v.z; c.w += v.w;
            ls[o] = c;
        }
    }
    __syncthreads();
    for (int idx = threadIdx.x; idx < G_ * 40; idx += blockDim.x) {
        float4 s = ls[idx];
        #pragma unroll
        for (int q = 1; q < 6; ++q) {
            float4 v = ls[q * G_ * 40 + idx];
            s.x += v.x; s.y += v.y; s.z += v.z; s.w += v.w;
        }
        int g = idx / 40, j = idx - g * 40;
        float* o = gsum + (size_t)g * XROW + j * 4;
        atomicAdd(o + 0, s.x); atomicAdd(o + 1, s.y);
        atomicAdd(o + 2, s.z); atomicAdd(o + 3, s.w);
    }
}

// feats = [op_mean, l2norm(op_sum), l2norm(cfg_sum)]; out = lrelu(feats@pw1)@pw2
__global__ void k_final(const float* __restrict__ osum, const float* __restrict__ gsum,
                        const float* __restrict__ cnt, const float* __restrict__ pw1,
                        const float* __restrict__ pw2, float* __restrict__ out) {
    __shared__ float sw1[3 * H_ * H_];
    __shared__ float sw2[H_];
    for (int i = threadIdx.x; i < 3 * H_ * H_; i += blockDim.x) sw1[i] = pw1[i];
    if (threadIdx.x < H_) sw2[threadIdx.x] = pw2[threadIdx.x];
    __syncthreads();
    int t = threadIdx.x;
    if (t >= G_ * C_) return;
    int g = t / C_;
    const float* os = osum + (size_t)t * H_;
    const float* cs = gsum + (size_t)t * H_;
    float icnt = 1.0f / cnt[g];
    float a0[H_], a1[H_], a2[H_];
    float s1 = 0.0f, s2 = 0.0f;
    #pragma unroll
    for (int h = 0; h < H_; ++h) {
        float v1 = os[h], v2 = cs[h];
        a0[h] = v1 * icnt;
        a1[h] = v1; s1 = fmaf(v1, v1, s1);
        a2[h] = v2; s2 = fmaf(v2, v2, s2);
    }
    float r1 = 1.0f / sqrtf(fmaxf(s1, 1e-12f));
    float r2 = 1.0f / sqrtf(fmaxf(s2, 1e-12f));
    #pragma unroll
    for (int h = 0; h < H_; ++h) { a1[h] *= r1; a2[h] *= r2; }
    float o = 0.0f;
    #pragma unroll
    for (int h = 0; h < H_; ++h) {
        float a = 0.0f;
        #pragma unroll
        for (int k = 0; k < H_; ++k) a = fmaf(a0[k], sw1[k * H_ + h], a);
        #pragma unroll
        for (int k = 0; k < H_; ++k) a = fmaf(a1[k], sw1[(H_ + k) * H_ + h], a);
        #pragma unroll
        for (int k = 0; k < H_; ++k) a = fmaf(a2[k], sw1[(2 * H_ + k) * H_ + h], a);
        o = fmaf(lrelu(a), sw2[h], o);
    }
    out[t] = o;
}

extern "C" void kernel_launch(void* const* d_in, const int* in_sizes, int n_in,
                              void* d_out, int out_size, void* d_ws, size_t ws_size,
                              hipStream_t stream) {
    const float* op_feats     = (const float*)d_in[0];
    const float* config_feats = (const float*)d_in[1];
    const int*   op_ids       = (const int*)d_in[2];
    const int*   selected     = (const int*)d_in[3];
    const int*   feed_src     = (const int*)d_in[4];
    const int*   feed_dst     = (const int*)d_in[5];
    const int*   sfeed_src    = (const int*)d_in[6];
    const int*   sfeed_dst    = (const int*)d_in[7];
    const int*   config_src   = (const int*)d_in[8];
    const int*   config_dst   = (const int*)d_in[9];
    const int*   sconfig_src  = (const int*)d_in[10];
    const int*   sconfig_dst  = (const int*)d_in[11];
    const int*   op_gid       = (const int*)d_in[12];
    const int*   cfg_gid      = (const int*)d_in[13];
    const float* emb          = (const float*)d_in[14];
    const float* pre_w1       = (const float*)d_in[15];
    const float* pre_b1       = (const float*)d_in[16];
    const float* pre_w2       = (const float*)d_in[17];
    const float* pre_b2       = (const float*)d_in[18];
    const float* gc_w1[2]     = {(const float*)d_in[19], (const float*)d_in[23]};
    const float* gc_b1[2]     = {(const float*)d_in[20], (const float*)d_in[24]};
    const float* gc_w2[2]     = {(const float*)d_in[21], (const float*)d_in[25]};
    const float* gc_b2[2]     = {(const float*)d_in[22], (const float*)d_in[26]};
    const float* post_w1      = (const float*)d_in[27];
    const float* post_w2      = (const float*)d_in[28];

    char* ws = (char*)d_ws;
    size_t off = 0;
    auto alloc = [&](size_t bytes) { void* p = ws + off; off += (bytes + 255) & ~(size_t)255; return p; };
    float* nfw  = (float*)alloc((size_t)N_ * H_ * 4);
    float* cfg  = (float*)alloc((size_t)N_ * CROW * 4);
    float* inv  = (float*)alloc((size_t)N_ * 4);
    int*   deg  = (int*)alloc((size_t)N_ * 4);
    float* xf   = (float*)alloc((size_t)N_ * XROW * 4);
    float* xb   = (float*)alloc((size_t)N_ * XROW * 4);
    float* csum = (float*)alloc((size_t)N_ * CROW * 4);
    float* xs   = (float*)alloc((size_t)N_ * XROW * 4);
    int*   roff = (int*)alloc((size_t)(N_ + 1) * 4);
    int*   cur  = (int*)alloc((size_t)N_ * 4);
    int*   aux  = (int*)alloc((size_t)512 * 4);
    int*   col  = (int*)alloc((size_t)2 * 160000 * 4);
    float* osum = (float*)alloc((size_t)G_ * XROW * 4);
    float* gsum = (float*)alloc((size_t)G_ * XROW * 4);
    float* cntb = (float*)alloc((size_t)G_ * 4);

    const int NB1 = CDIV(N_, 256);   // 313 scan blocks

    k_nfw<<<CDIV(N_ * H_, 256), 256, 0, stream>>>(op_feats, op_ids, emb, pre_w1, pre_b1, nfw);

    for (int fwd = 0; fwd < 2; ++fwd) {
        const int* esrc = fwd ? sfeed_src : feed_src;
        const int* edst = fwd ? sfeed_dst : feed_dst;
        int Ecur = fwd ? in_sizes[6] : in_sizes[4];
        const int* csrc = fwd ? sconfig_src : config_src;
        const int* cdst = fwd ? sconfig_dst : config_dst;
        float* x = fwd ? xb : xf;

        hipMemsetAsync(cfg, 0, (size_t)N_ * CROW * 4, stream);
        hipMemsetAsync(deg, 0, (size_t)N_ * 4, stream);
        k_cfg_scatter<<<CDIV(NC_ * CROW, 256), 256, 0, stream>>>(config_feats, csrc, cdst, cfg);
        k_deg<<<CDIV(Ecur, 256), 256, 0, stream>>>(esrc, edst, Ecur, deg);
        k_inv<<<CDIV(N_, 256), 256, 0, stream>>>(deg, inv);
        // CSR build
        k_scan1<<<NB1, 256, 0, stream>>>(deg, roff, aux);
        k_scan2<<<1, 512, 0, stream>>>(aux, NB1);
        k_scan3<<<CDIV(N_, 256), 256, 0, stream>>>(roff, aux, cur, 2 * Ecur);
        k_fill<<<CDIV(Ecur, 256), 256, 0, stream>>>(esrc, edst, Ecur, cur, col);

        k_csum_gather<<<CDIV(N_ * 45, 256), 256, 0, stream>>>((const float2*)cfg, inv, roff, col,
                                                              (float2*)csum);
        k_pre<<<CDIV(N_ * C_, TR), 256, 0, stream>>>(cfg, nfw, pre_w1, pre_w2, pre_b2, x);

        for (int l = 0; l < 2; ++l) {
            k_xs_gather<<<CDIV(N_ * 40, 256), 256, 0, stream>>>((const float4*)x, inv, roff, col,
                                                                (float4*)xs);
            k_gcmlp<<<CDIV(N_ * C_, TR), 256, 0, stream>>>(csum, xs, inv, gc_w1[l], gc_b1[l],
                                                           gc_w2[l], gc_b2[l], x);
        }
    }

    hipMemsetAsync(osum, 0, (size_t)G_ * XROW * 4, stream);
    hipMemsetAsync(gsum, 0, (size_t)G_ * XROW * 4, stream);
    hipMemsetAsync(cntb, 0, (size_t)G_ * 4, stream);
    k_opsum<<<512, 256, 0, stream>>>((const float4*)xf, (const float4*)xb, selected, op_gid, osum, cntb);
    k_cfgsum<<<64, 256, 0, stream>>>((const float4*)xf, (const float4*)xb, selected,
                                     config_src, config_dst, cfg_gid, gsum);
    k_final<<<1, 128, 0, stream>>>(osum, gsum, cntb, post_w1, post_w2, (float*)d_out);
}

// Round 5
// 959.217 us; speedup vs baseline: 3.5569x; 1.2159x over previous
//
#include <hip/hip_runtime.h>
#include <hip/hip_bf16.h>
#include <math.h>

#define CDIV(a,b) (((a)+(b)-1)/(b))

constexpr int N_   = 80000;
constexpr int NC_  = 8000;
constexpr int G_   = 16;
constexpr int C_   = 5;
constexpr int CFGF = 18;
constexpr int OPF  = 140;
constexpr int OPE  = 32;
constexpr int H_   = 32;
constexpr int NUMOPS = 120;
constexpr int CROW = C_ * CFGF;   // 90
constexpr int XROW = C_ * H_;     // 160
constexpr float ALPHA_ = 0.2f;

__device__ __forceinline__ float lrelu(float v) { return v >= 0.0f ? v : ALPHA_ * v; }

// nfwop[op][h] = pre_b1[h] + emb[op] @ w1[158:190]  (tiny: 120x32)
__global__ void k_nfwop(const float* __restrict__ emb, const float* __restrict__ w1,
                        const float* __restrict__ b1, float* __restrict__ nfwop) {
    int t = blockIdx.x * blockDim.x + threadIdx.x;
    if (t >= NUMOPS * H_) return;
    int op = t >> 5, h = t & 31;
    float a = b1[h];
    for (int e = 0; e < OPE; ++e)
        a = fmaf(emb[op * OPE + e], w1[(CFGF + OPF + e) * H_ + h], a);
    nfwop[t] = a;
}

// nfw[n][:] = nfwop[op_ids[n]][:] + op_feats[n] @ w1[18:158]
// one thread per node; 32 accumulators; weights via lane-uniform (scalar) loads
__global__ void k_nfw(const float* __restrict__ opf, const int* __restrict__ op_ids,
                      const float* __restrict__ nfwop, const float* __restrict__ w1,
                      float* __restrict__ nfw) {
    int n = blockIdx.x * blockDim.x + threadIdx.x;
    if (n >= N_) return;
    float acc[H_];
    const float4* it = (const float4*)(nfwop + (size_t)op_ids[n] * H_);
    #pragma unroll
    for (int q = 0; q < 8; ++q) {
        float4 v = it[q];
        acc[4 * q + 0] = v.x; acc[4 * q + 1] = v.y; acc[4 * q + 2] = v.z; acc[4 * q + 3] = v.w;
    }
    const float4* f4 = (const float4*)(opf + (size_t)n * OPF);
    const float* wf = w1 + CFGF * H_;   // rows 18..157
    for (int kc = 0; kc < OPF / 4; ++kc) {
        float4 rv = f4[kc];
        float rs[4] = {rv.x, rv.y, rv.z, rv.w};
        #pragma unroll
        for (int j = 0; j < 4; ++j) {
            int k = kc * 4 + j;
            #pragma unroll
            for (int h = 0; h < H_; ++h) acc[h] = fmaf(rs[j], wf[k * H_ + h], acc[h]);
        }
    }
    float4* o = (float4*)(nfw + (size_t)n * H_);
    #pragma unroll
    for (int q = 0; q < 8; ++q)
        o[q] = make_float4(acc[4 * q], acc[4 * q + 1], acc[4 * q + 2], acc[4 * q + 3]);
}

// cfg[cdst[i]][c][f] += 100 * config_feats[csrc[i]][c][f]
__global__ void k_cfg_scatter(const float* __restrict__ cf, const int* __restrict__ csrc,
                              const int* __restrict__ cdst, float* __restrict__ cfg) {
    int t = blockIdx.x * blockDim.x + threadIdx.x;
    if (t >= NC_ * CROW) return;
    int i = t / CROW, j = t - i * CROW;
    int s = csrc[i], d = cdst[i];
    atomicAdd(&cfg[(size_t)d * CROW + j], 100.0f * cf[(size_t)s * CROW + j]);
}

__global__ void k_deg(const int* __restrict__ src, const int* __restrict__ dst,
                      int E, int* __restrict__ deg) {
    int e = blockIdx.x * blockDim.x + threadIdx.x;
    if (e >= E) return;
    atomicAdd(&deg[src[e]], 1);
    atomicAdd(&deg[dst[e]], 1);
}

__global__ void k_inv(const int* __restrict__ deg, float* __restrict__ inv) {
    int n = blockIdx.x * blockDim.x + threadIdx.x;
    if (n >= N_) return;
    inv[n] = 1.0f / sqrtf((float)(deg[n] + 1));   // +1 self loop
}

// ---- CSR build ----
__global__ void k_scan1(const int* __restrict__ deg, int* __restrict__ roff, int* __restrict__ aux) {
    __shared__ int s[256];
    int t = threadIdx.x, n = blockIdx.x * 256 + t;
    int v = (n < N_) ? deg[n] : 0;
    s[t] = v; __syncthreads();
    for (int off = 1; off < 256; off <<= 1) {
        int x = (t >= off) ? s[t - off] : 0;
        __syncthreads();
        s[t] += x;
        __syncthreads();
    }
    if (n < N_) roff[n] = s[t] - v;
    if (t == 255) aux[blockIdx.x] = s[255];
}

__global__ void k_scan2(int* __restrict__ aux, int nb) {
    __shared__ int s[512];
    int t = threadIdx.x;
    int v = (t < nb) ? aux[t] : 0;
    s[t] = v; __syncthreads();
    for (int off = 1; off < 512; off <<= 1) {
        int x = (t >= off) ? s[t - off] : 0;
        __syncthreads();
        s[t] += x;
        __syncthreads();
    }
    if (t < nb) aux[t] = s[t] - v;
}

__global__ void k_scan3(int* __restrict__ roff, const int* __restrict__ aux,
                        int* __restrict__ cur, int total) {
    int n = blockIdx.x * blockDim.x + threadIdx.x;
    if (n < N_) {
        int r = roff[n] + aux[n >> 8];
        roff[n] = r;
        cur[n] = r;
    }
    if (n == 0) roff[N_] = total;
}

__global__ void k_fill(const int* __restrict__ src, const int* __restrict__ dst, int E,
                       int* __restrict__ cur, int* __restrict__ col) {
    int e = blockIdx.x * blockDim.x + threadIdx.x;
    if (e >= E) return;
    int s = src[e], d = dst[e];
    col[atomicAdd(&cur[d], 1)] = s;
    col[atomicAdd(&cur[s], 1)] = d;
}

// ---- gathers (self + CSR neighbors) ----
__global__ void k_csum_gather(const float2* __restrict__ cfg2, const float* __restrict__ inv,
                              const int* __restrict__ roff, const int* __restrict__ col,
                              float2* __restrict__ csum2) {
    int t = blockIdx.x * blockDim.x + threadIdx.x;
    if (t >= N_ * 45) return;
    int n = t / 45, j2 = t - n * 45;
    float iv = inv[n];
    float2 a = cfg2[t];
    a.x *= iv; a.y *= iv;
    int p1 = roff[n + 1];
    for (int p = roff[n]; p < p1; ++p) {
        int s = col[p];
        float ivs = inv[s];
        float2 v = cfg2[(size_t)s * 45 + j2];
        a.x = fmaf(v.x, ivs, a.x);
        a.y = fmaf(v.y, ivs, a.y);
    }
    csum2[t] = a;
}

__global__ void k_xs_gather(const float4* __restrict__ x4, const float* __restrict__ inv,
                            const int* __restrict__ roff, const int* __restrict__ col,
                            float4* __restrict__ xs4) {
    int t = blockIdx.x * blockDim.x + threadIdx.x;
    if (t >= N_ * 40) return;
    int n = t / 40, j4 = t - n * 40;
    float iv = inv[n];
    float4 a = x4[t];
    a.x *= iv; a.y *= iv; a.z *= iv; a.w *= iv;
    int p1 = roff[n + 1];
    for (int p = roff[n]; p < p1; ++p) {
        int s = col[p];
        float ivs = inv[s];
        float4 v = x4[(size_t)s * 40 + j4];
        a.x = fmaf(v.x, ivs, a.x);
        a.y = fmaf(v.y, ivs, a.y);
        a.z = fmaf(v.z, ivs, a.z);
        a.w = fmaf(v.w, ivs, a.w);
    }
    xs4[t] = a;
}

// pre-MLP, one thread per row r: x[r] = lrelu(lrelu(nfw[n] + cfg[r]@w1c) @ w2 + b2)
__global__ void k_pre(const float* __restrict__ cfg, const float* __restrict__ nfw,
                      const float* __restrict__ w1, const float* __restrict__ w2,
                      const float* __restrict__ b2, float* __restrict__ x) {
    int r = blockIdx.x * blockDim.x + threadIdx.x;
    if (r >= N_ * C_) return;
    int n = r / C_;
    float h1[H_];
    const float4* nf4 = (const float4*)(nfw + (size_t)n * H_);
    #pragma unroll
    for (int q = 0; q < 8; ++q) {
        float4 v = nf4[q];
        h1[4 * q + 0] = v.x; h1[4 * q + 1] = v.y; h1[4 * q + 2] = v.z; h1[4 * q + 3] = v.w;
    }
    const float2* c2 = (const float2*)(cfg + (size_t)r * CFGF);
    for (int kc = 0; kc < CFGF / 2; ++kc) {
        float2 cv = c2[kc];
        float cs[2] = {cv.x, cv.y};
        #pragma unroll
        for (int j = 0; j < 2; ++j) {
            int k = kc * 2 + j;
            #pragma unroll
            for (int h = 0; h < H_; ++h) h1[h] = fmaf(cs[j], w1[k * H_ + h], h1[h]);
        }
    }
    #pragma unroll
    for (int h = 0; h < H_; ++h) h1[h] = lrelu(h1[h]);
    float acc[H_];
    #pragma unroll
    for (int h = 0; h < H_; ++h) acc[h] = b2[h];
    #pragma unroll
    for (int k = 0; k < H_; ++k) {
        float v = h1[k];
        #pragma unroll
        for (int h = 0; h < H_; ++h) acc[h] = fmaf(v, w2[k * H_ + h], acc[h]);
    }
    float4* o = (float4*)(x + (size_t)r * H_);
    #pragma unroll
    for (int q = 0; q < 8; ++q)
        o[q] = make_float4(lrelu(acc[4 * q]), lrelu(acc[4 * q + 1]),
                           lrelu(acc[4 * q + 2]), lrelu(acc[4 * q + 3]));
}

// GC MLP, one thread per row: x[r] += lrelu(lrelu(b1 + inv*(csum[r]@w1c + xs[r]@w1x)) @ w2 + b2)
__global__ void k_gcmlp(const float* __restrict__ csum, const float* __restrict__ xsin,
                        const float* __restrict__ inv,
                        const float* __restrict__ w1, const float* __restrict__ b1,
                        const float* __restrict__ w2, const float* __restrict__ b2,
                        float* __restrict__ x) {
    int r = blockIdx.x * blockDim.x + threadIdx.x;
    if (r >= N_ * C_) return;
    int n = r / C_;
    float iv = inv[n];
    float t1[H_];
    #pragma unroll
    for (int h = 0; h < H_; ++h) t1[h] = 0.0f;
    const float2* c2 = (const float2*)(csum + (size_t)r * CFGF);
    for (int kc = 0; kc < CFGF / 2; ++kc) {
        float2 cv = c2[kc];
        float cs[2] = {cv.x, cv.y};
        #pragma unroll
        for (int j = 0; j < 2; ++j) {
            int k = kc * 2 + j;
            #pragma unroll
            for (int h = 0; h < H_; ++h) t1[h] = fmaf(cs[j], w1[k * H_ + h], t1[h]);
        }
    }
    const float4* xs4 = (const float4*)(xsin + (size_t)r * H_);
    for (int kc = 0; kc < H_ / 4; ++kc) {
        float4 xv = xs4[kc];
        float xsv[4] = {xv.x, xv.y, xv.z, xv.w};
        #pragma unroll
        for (int j = 0; j < 4; ++j) {
            int k = kc * 4 + j;
            #pragma unroll
            for (int h = 0; h < H_; ++h)
                t1[h] = fmaf(xsv[j], w1[(CFGF + k) * H_ + h], t1[h]);
        }
    }
    float h1[H_];
    #pragma unroll
    for (int h = 0; h < H_; ++h) h1[h] = lrelu(fmaf(iv, t1[h], b1[h]));
    float acc[H_];
    #pragma unroll
    for (int h = 0; h < H_; ++h) acc[h] = b2[h];
    #pragma unroll
    for (int k = 0; k < H_; ++k) {
        float v = h1[k];
        #pragma unroll
        for (int h = 0; h < H_; ++h) acc[h] = fmaf(v, w2[k * H_ + h], acc[h]);
    }
    float4* o = (float4*)(x + (size_t)r * H_);
    #pragma unroll
    for (int q = 0; q < 8; ++q) {
        float4 v = o[q];
        v.x += lrelu(acc[4 * q]); v.y += lrelu(acc[4 * q + 1]);
        v.z += lrelu(acc[4 * q + 2]); v.w += lrelu(acc[4 * q + 3]);
        o[q] = v;
    }
}

// op_sum: 512 blocks x 256 thr; 6 node-slots x 40 float4-lanes; private LDS per slot
__global__ void k_opsum(const float4* __restrict__ xf4, const float4* __restrict__ xb4,
                        const int* __restrict__ sel, const int* __restrict__ gid,
                        float* __restrict__ osum, float* __restrict__ cnt) {
    __shared__ float4 ls[6 * G_ * 40];
    __shared__ float lc[6 * G_];
    for (int i = threadIdx.x; i < 6 * G_ * 40; i += blockDim.x) ls[i] = make_float4(0.f, 0.f, 0.f, 0.f);
    if (threadIdx.x < 6 * G_) lc[threadIdx.x] = 0.0f;
    __syncthreads();
    int j4 = threadIdx.x % 40, i = threadIdx.x / 40;
    const int NPB = CDIV(N_, 512);
    int start = blockIdx.x * NPB;
    int end = min(start + NPB, N_);
    if (i < 6) {
        for (int n = start + i; n < end; n += 6) {
            int g = gid[n];
            const float4* xr = sel[n] ? xb4 : xf4;
            float4 v = xr[(size_t)n * 40 + j4];
            int o = (i * G_ + g) * 40 + j4;
            float4 c = ls[o];
            c.x += v.x; c.y += v.y; c.z += v.z; c.w += v.w;
            ls[o] = c;
            if (j4 == 0) lc[i * G_ + g] += 1.0f;
        }
    }
    __syncthreads();
    for (int idx = threadIdx.x; idx < G_ * 40; idx += blockDim.x) {
        float4 s = ls[idx];
        #pragma unroll
        for (int q = 1; q < 6; ++q) {
            float4 v = ls[q * G_ * 40 + idx];
            s.x += v.x; s.y += v.y; s.z += v.z; s.w += v.w;
        }
        int g = idx / 40, j = idx - g * 40;
        float* o = osum + (size_t)g * XROW + j * 4;
        atomicAdd(o + 0, s.x); atomicAdd(o + 1, s.y);
        atomicAdd(o + 2, s.z); atomicAdd(o + 3, s.w);
    }
    if (threadIdx.x < G_) {
        float c = 0.0f;
        #pragma unroll
        for (int q = 0; q < 6; ++q) c += lc[q * G_ + threadIdx.x];
        atomicAdd(&cnt[threadIdx.x], c);
    }
}

// cfg_sum: 64 blocks x 256 thr
__global__ void k_cfgsum(const float4* __restrict__ xf4, const float4* __restrict__ xb4,
                         const int* __restrict__ sel, const int* __restrict__ csrc,
                         const int* __restrict__ cdst, const int* __restrict__ cfg_gid,
                         float* __restrict__ gsum) {
    __shared__ float4 ls[6 * G_ * 40];
    for (int i = threadIdx.x; i < 6 * G_ * 40; i += blockDim.x) ls[i] = make_float4(0.f, 0.f, 0.f, 0.f);
    __syncthreads();
    int j4 = threadIdx.x % 40, i = threadIdx.x / 40;
    const int EPB = CDIV(NC_, 64);
    int start = blockIdx.x * EPB;
    int end = min(start + EPB, NC_);
    if (i < 6) {
        for (int e = start + i; e < end; e += 6) {
            int g = cfg_gid[csrc[e]];
            int n = cdst[e];
            const float4* xr = sel[n] ? xb4 : xf4;
            float4 v = xr[(size_t)n * 40 + j4];
            int o = (i * G_ + g) * 40 + j4;
            float4 c = ls[o];
            c.x += v.x; c.y += v.y; c.z += v.z; c.w += v.w;
            ls[o] = c;
        }
    }
    __syncthreads();
    for (int idx = threadIdx.x; idx < G_ * 40; idx += blockDim.x) {
        float4 s = ls[idx];
        #pragma unroll
        for (int q = 1; q < 6; ++q) {
            float4 v = ls[q * G_ * 40 + idx];
            s.x += v.x; s.y += v.y; s.z += v.z; s.w += v.w;
        }
        int g = idx / 40, j = idx - g * 40;
        float* o = gsum + (size_t)g * XROW + j * 4;
        atomicAdd(o + 0, s.x); atomicAdd(o + 1, s.y);
        atomicAdd(o + 2, s.z); atomicAdd(o + 3, s.w);
    }
}

__global__ void k_final(const float* __restrict__ osum, const float* __restrict__ gsum,
                        const float* __restrict__ cnt, const float* __restrict__ pw1,
                        const float* __restrict__ pw2, float* __restrict__ out) {
    __shared__ float sw1[3 * H_ * H_];
    __shared__ float sw2[H_];
    for (int i = threadIdx.x; i < 3 * H_ * H_; i += blockDim.x) sw1[i] = pw1[i];
    if (threadIdx.x < H_) sw2[threadIdx.x] = pw2[threadIdx.x];
    __syncthreads();
    int t = threadIdx.x;
    if (t >= G_ * C_) return;
    int g = t / C_;
    const float* os = osum + (size_t)t * H_;
    const float* cs = gsum + (size_t)t * H_;
    float icnt = 1.0f / cnt[g];
    float a0[H_], a1[H_], a2[H_];
    float s1 = 0.0f, s2 = 0.0f;
    #pragma unroll
    for (int h = 0; h < H_; ++h) {
        float v1 = os[h], v2 = cs[h];
        a0[h] = v1 * icnt;
        a1[h] = v1; s1 = fmaf(v1, v1, s1);
        a2[h] = v2; s2 = fmaf(v2, v2, s2);
    }
    float r1 = 1.0f / sqrtf(fmaxf(s1, 1e-12f));
    float r2 = 1.0f / sqrtf(fmaxf(s2, 1e-12f));
    #pragma unroll
    for (int h = 0; h < H_; ++h) { a1[h] *= r1; a2[h] *= r2; }
    float o = 0.0f;
    #pragma unroll
    for (int h = 0; h < H_; ++h) {
        float a = 0.0f;
        #pragma unroll
        for (int k = 0; k < H_; ++k) a = fmaf(a0[k], sw1[k * H_ + h], a);
        #pragma unroll
        for (int k = 0; k < H_; ++k) a = fmaf(a1[k], sw1[(H_ + k) * H_ + h], a);
        #pragma unroll
        for (int k = 0; k < H_; ++k) a = fmaf(a2[k], sw1[(2 * H_ + k) * H_ + h], a);
        o = fmaf(lrelu(a), sw2[h], o);
    }
    out[t] = o;
}

extern "C" void kernel_launch(void* const* d_in, const int* in_sizes, int n_in,
                              void* d_out, int out_size, void* d_ws, size_t ws_size,
                              hipStream_t stream) {
    const float* op_feats     = (const float*)d_in[0];
    const float* config_feats = (const float*)d_in[1];
    const int*   op_ids       = (const int*)d_in[2];
    const int*   selected     = (const int*)d_in[3];
    const int*   feed_src     = (const int*)d_in[4];
    const int*   feed_dst     = (const int*)d_in[5];
    const int*   sfeed_src    = (const int*)d_in[6];
    const int*   sfeed_dst    = (const int*)d_in[7];
    const int*   config_src   = (const int*)d_in[8];
    const int*   config_dst   = (const int*)d_in[9];
    const int*   sconfig_src  = (const int*)d_in[10];
    const int*   sconfig_dst  = (const int*)d_in[11];
    const int*   op_gid       = (const int*)d_in[12];
    const int*   cfg_gid      = (const int*)d_in[13];
    const float* emb          = (const float*)d_in[14];
    const float* pre_w1       = (const float*)d_in[15];
    const float* pre_b1       = (const float*)d_in[16];
    const float* pre_w2       = (const float*)d_in[17];
    const float* pre_b2       = (const float*)d_in[18];
    const float* gc_w1[2]     = {(const float*)d_in[19], (const float*)d_in[23]};
    const float* gc_b1[2]     = {(const float*)d_in[20], (const float*)d_in[24]};
    const float* gc_w2[2]     = {(const float*)d_in[21], (const float*)d_in[25]};
    const float* gc_b2[2]     = {(const float*)d_in[22], (const float*)d_in[26]};
    const float* post_w1      = (const float*)d_in[27];
    const float* post_w2      = (const float*)d_in[28];

    char* ws = (char*)d_ws;
    size_t off = 0;
    auto alloc = [&](size_t bytes) { void* p = ws + off; off += (bytes + 255) & ~(size_t)255; return p; };
    float* nfw  = (float*)alloc((size_t)N_ * H_ * 4);
    float* nfwop= (float*)alloc((size_t)NUMOPS * H_ * 4);
    float* cfg  = (float*)alloc((size_t)N_ * CROW * 4);
    float* inv  = (float*)alloc((size_t)N_ * 4);
    int*   deg  = (int*)alloc((size_t)N_ * 4);
    float* xf   = (float*)alloc((size_t)N_ * XROW * 4);
    float* xb   = (float*)alloc((size_t)N_ * XROW * 4);
    float* csum = (float*)alloc((size_t)N_ * CROW * 4);
    float* xs   = (float*)alloc((size_t)N_ * XROW * 4);
    int*   roff = (int*)alloc((size_t)(N_ + 1) * 4);
    int*   cur  = (int*)alloc((size_t)N_ * 4);
    int*   aux  = (int*)alloc((size_t)512 * 4);
    int*   col  = (int*)alloc((size_t)2 * 160000 * 4);
    float* osum = (float*)alloc((size_t)G_ * XROW * 4);
    float* gsum = (float*)alloc((size_t)G_ * XROW * 4);
    float* cntb = (float*)alloc((size_t)G_ * 4);

    const int NB1 = CDIV(N_, 256);

    k_nfwop<<<CDIV(NUMOPS * H_, 256), 256, 0, stream>>>(emb, pre_w1, pre_b1, nfwop);
    k_nfw<<<CDIV(N_, 256), 256, 0, stream>>>(op_feats, op_ids, nfwop, pre_w1, nfw);

    for (int fwd = 0; fwd < 2; ++fwd) {
        const int* esrc = fwd ? sfeed_src : feed_src;
        const int* edst = fwd ? sfeed_dst : feed_dst;
        int Ecur = fwd ? in_sizes[6] : in_sizes[4];
        const int* csrc = fwd ? sconfig_src : config_src;
        const int* cdst = fwd ? sconfig_dst : config_dst;
        float* x = fwd ? xb : xf;

        hipMemsetAsync(cfg, 0, (size_t)N_ * CROW * 4, stream);
        hipMemsetAsync(deg, 0, (size_t)N_ * 4, stream);
        k_cfg_scatter<<<CDIV(NC_ * CROW, 256), 256, 0, stream>>>(config_feats, csrc, cdst, cfg);
        k_deg<<<CDIV(Ecur, 256), 256, 0, stream>>>(esrc, edst, Ecur, deg);
        k_inv<<<CDIV(N_, 256), 256, 0, stream>>>(deg, inv);
        k_scan1<<<NB1, 256, 0, stream>>>(deg, roff, aux);
        k_scan2<<<1, 512, 0, stream>>>(aux, NB1);
        k_scan3<<<CDIV(N_, 256), 256, 0, stream>>>(roff, aux, cur, 2 * Ecur);
        k_fill<<<CDIV(Ecur, 256), 256, 0, stream>>>(esrc, edst, Ecur, cur, col);

        k_csum_gather<<<CDIV(N_ * 45, 256), 256, 0, stream>>>((const float2*)cfg, inv, roff, col,
                                                              (float2*)csum);
        k_pre<<<CDIV(N_ * C_, 256), 256, 0, stream>>>(cfg, nfw, pre_w1, pre_w2, pre_b2, x);

        for (int l = 0; l < 2; ++l) {
            k_xs_gather<<<CDIV(N_ * 40, 256), 256, 0, stream>>>((const float4*)x, inv, roff, col,
                                                                (float4*)xs);
            k_gcmlp<<<CDIV(N_ * C_, 256), 256, 0, stream>>>(csum, xs, inv, gc_w1[l], gc_b1[l],
                                                            gc_w2[l], gc_b2[l], x);
        }
    }

    hipMemsetAsync(osum, 0, (size_t)G_ * XROW * 4, stream);
    hipMemsetAsync(gsum, 0, (size_t)G_ * XROW * 4, stream);
    hipMemsetAsync(cntb, 0, (size_t)G_ * 4, stream);
    k_opsum<<<512, 256, 0, stream>>>((const float4*)xf, (const float4*)xb, selected, op_gid, osum, cntb);
    k_cfgsum<<<64, 256, 0, stream>>>((const float4*)xf, (const float4*)xb, selected,
                                     config_src, config_dst, cfg_gid, gsum);
    k_final<<<1, 128, 0, stream>>>(osum, gsum, cntb, post_w1, post_w2, (float*)d_out);
}

// Round 6
// 751.559 us; speedup vs baseline: 4.5397x; 1.2763x over previous
//
#include <hip/hip_runtime.h>
#include <hip/hip_bf16.h>
#include <math.h>

#define CDIV(a,b) (((a)+(b)-1)/(b))

constexpr int N_   = 80000;
constexpr int NC_  = 8000;
constexpr int G_   = 16;
constexpr int C_   = 5;
constexpr int CFGF = 18;
constexpr int OPF  = 140;
constexpr int OPE  = 32;
constexpr int H_   = 32;
constexpr int NUMOPS = 120;
constexpr int CROW = C_ * CFGF;   // 90
constexpr int XROW = C_ * H_;     // 160
constexpr float ALPHA_ = 0.2f;

__device__ __forceinline__ float lrelu(float v) { return v >= 0.0f ? v : ALPHA_ * v; }

// nfwop[op][h] = pre_b1[h] + emb[op] @ w1[158:190]  (tiny: 120x32)
__global__ void k_nfwop(const float* __restrict__ emb, const float* __restrict__ w1,
                        const float* __restrict__ b1, float* __restrict__ nfwop) {
    int t = blockIdx.x * blockDim.x + threadIdx.x;
    if (t >= NUMOPS * H_) return;
    int op = t >> 5, h = t & 31;
    float a = b1[h];
    for (int e = 0; e < OPE; ++e)
        a = fmaf(emb[op * OPE + e], w1[(CFGF + OPF + e) * H_ + h], a);
    nfwop[t] = a;
}

// nfw[n][:] = nfwop[op_ids[n]][:] + op_feats[n] @ w1[18:158]
__global__ void k_nfw(const float* __restrict__ opf, const int* __restrict__ op_ids,
                      const float* __restrict__ nfwop, const float* __restrict__ w1,
                      float* __restrict__ nfw) {
    int n = blockIdx.x * blockDim.x + threadIdx.x;
    if (n >= N_) return;
    float acc[H_];
    const float4* it = (const float4*)(nfwop + (size_t)op_ids[n] * H_);
    #pragma unroll
    for (int q = 0; q < 8; ++q) {
        float4 v = it[q];
        acc[4 * q + 0] = v.x; acc[4 * q + 1] = v.y; acc[4 * q + 2] = v.z; acc[4 * q + 3] = v.w;
    }
    const float4* f4 = (const float4*)(opf + (size_t)n * OPF);
    const float* wf = w1 + CFGF * H_;   // rows 18..157
    for (int kc = 0; kc < OPF / 4; ++kc) {
        float4 rv = f4[kc];
        float rs[4] = {rv.x, rv.y, rv.z, rv.w};
        #pragma unroll
        for (int j = 0; j < 4; ++j) {
            int k = kc * 4 + j;
            #pragma unroll
            for (int h = 0; h < H_; ++h) acc[h] = fmaf(rs[j], wf[k * H_ + h], acc[h]);
        }
    }
    float4* o = (float4*)(nfw + (size_t)n * H_);
    #pragma unroll
    for (int q = 0; q < 8; ++q)
        o[q] = make_float4(acc[4 * q], acc[4 * q + 1], acc[4 * q + 2], acc[4 * q + 3]);
}

// cfg[cdst[i]][c][f] += 100 * config_feats[csrc[i]][c][f]
__global__ void k_cfg_scatter(const float* __restrict__ cf, const int* __restrict__ csrc,
                              const int* __restrict__ cdst, float* __restrict__ cfg) {
    int t = blockIdx.x * blockDim.x + threadIdx.x;
    if (t >= NC_ * CROW) return;
    int i = t / CROW, j = t - i * CROW;
    int s = csrc[i], d = cdst[i];
    atomicAdd(&cfg[(size_t)d * CROW + j], 100.0f * cf[(size_t)s * CROW + j]);
}

__global__ void k_deg(const int* __restrict__ src, const int* __restrict__ dst,
                      int E, int* __restrict__ deg) {
    int e = blockIdx.x * blockDim.x + threadIdx.x;
    if (e >= E) return;
    atomicAdd(&deg[src[e]], 1);
    atomicAdd(&deg[dst[e]], 1);
}

__global__ void k_inv(const int* __restrict__ deg, float* __restrict__ inv) {
    int n = blockIdx.x * blockDim.x + threadIdx.x;
    if (n >= N_) return;
    inv[n] = 1.0f / sqrtf((float)(deg[n] + 1));   // +1 self loop
}

// ---- CSR build ----
__global__ void k_scan1(const int* __restrict__ deg, int* __restrict__ roff, int* __restrict__ aux) {
    __shared__ int s[256];
    int t = threadIdx.x, n = blockIdx.x * 256 + t;
    int v = (n < N_) ? deg[n] : 0;
    s[t] = v; __syncthreads();
    for (int off = 1; off < 256; off <<= 1) {
        int x = (t >= off) ? s[t - off] : 0;
        __syncthreads();
        s[t] += x;
        __syncthreads();
    }
    if (n < N_) roff[n] = s[t] - v;
    if (t == 255) aux[blockIdx.x] = s[255];
}

__global__ void k_scan2(int* __restrict__ aux, int nb) {
    __shared__ int s[512];
    int t = threadIdx.x;
    int v = (t < nb) ? aux[t] : 0;
    s[t] = v; __syncthreads();
    for (int off = 1; off < 512; off <<= 1) {
        int x = (t >= off) ? s[t - off] : 0;
        __syncthreads();
        s[t] += x;
        __syncthreads();
    }
    if (t < nb) aux[t] = s[t] - v;
}

__global__ void k_scan3(int* __restrict__ roff, const int* __restrict__ aux,
                        int* __restrict__ cur, int total) {
    int n = blockIdx.x * blockDim.x + threadIdx.x;
    if (n < N_) {
        int r = roff[n] + aux[n >> 8];
        roff[n] = r;
        cur[n] = r;
    }
    if (n == 0) roff[N_] = total;
}

__global__ void k_fill(const int* __restrict__ src, const int* __restrict__ dst, int E,
                       int* __restrict__ cur, int* __restrict__ col) {
    int e = blockIdx.x * blockDim.x + threadIdx.x;
    if (e >= E) return;
    int s = src[e], d = dst[e];
    col[atomicAdd(&cur[d], 1)] = s;
    col[atomicAdd(&cur[s], 1)] = d;
}

// csum[n][j2] = inv[n]*cfg[n][j2] + sum_s inv[s]*cfg[s][j2]
__global__ void k_csum_gather(const float2* __restrict__ cfg2, const float* __restrict__ inv,
                              const int* __restrict__ roff, const int* __restrict__ col,
                              float2* __restrict__ csum2) {
    int t = blockIdx.x * blockDim.x + threadIdx.x;
    if (t >= N_ * 45) return;
    int n = t / 45, j2 = t - n * 45;
    float iv = inv[n];
    float2 a = cfg2[t];
    a.x *= iv; a.y *= iv;
    int p1 = roff[n + 1];
    for (int p = roff[n]; p < p1; ++p) {
        int s = col[p];
        float ivs = inv[s];
        float2 v = cfg2[(size_t)s * 45 + j2];
        a.x = fmaf(v.x, ivs, a.x);
        a.y = fmaf(v.y, ivs, a.y);
    }
    csum2[t] = a;
}

// pre-MLP, one thread per row r: x[r] = lrelu(lrelu(nfw[n] + cfg[r]@w1c) @ w2 + b2)
__global__ void k_pre(const float* __restrict__ cfg, const float* __restrict__ nfw,
                      const float* __restrict__ w1, const float* __restrict__ w2,
                      const float* __restrict__ b2, float* __restrict__ x) {
    int r = blockIdx.x * blockDim.x + threadIdx.x;
    if (r >= N_ * C_) return;
    int n = r / C_;
    float h1[H_];
    const float4* nf4 = (const float4*)(nfw + (size_t)n * H_);
    #pragma unroll
    for (int q = 0; q < 8; ++q) {
        float4 v = nf4[q];
        h1[4 * q + 0] = v.x; h1[4 * q + 1] = v.y; h1[4 * q + 2] = v.z; h1[4 * q + 3] = v.w;
    }
    const float2* c2 = (const float2*)(cfg + (size_t)r * CFGF);
    for (int kc = 0; kc < CFGF / 2; ++kc) {
        float2 cv = c2[kc];
        float cs[2] = {cv.x, cv.y};
        #pragma unroll
        for (int j = 0; j < 2; ++j) {
            int k = kc * 2 + j;
            #pragma unroll
            for (int h = 0; h < H_; ++h) h1[h] = fmaf(cs[j], w1[k * H_ + h], h1[h]);
        }
    }
    #pragma unroll
    for (int h = 0; h < H_; ++h) h1[h] = lrelu(h1[h]);
    float acc[H_];
    #pragma unroll
    for (int h = 0; h < H_; ++h) acc[h] = b2[h];
    #pragma unroll
    for (int k = 0; k < H_; ++k) {
        float v = h1[k];
        #pragma unroll
        for (int h = 0; h < H_; ++h) acc[h] = fmaf(v, w2[k * H_ + h], acc[h]);
    }
    float4* o = (float4*)(x + (size_t)r * H_);
    #pragma unroll
    for (int q = 0; q < 8; ++q)
        o[q] = make_float4(lrelu(acc[4 * q]), lrelu(acc[4 * q + 1]),
                           lrelu(acc[4 * q + 2]), lrelu(acc[4 * q + 3]));
}

// FUSED gather + GC-MLP. One thread per row r=(n,c):
//   xs = inv[n]*xin[r] + sum_{s in nbr(n)} inv[s]*xin[s*C+c]      (registers)
//   t1 = csum[r]@w1[0:18] + xs@w1[18:50]
//   xout[r] = xin[r] + lrelu(lrelu(b1 + inv[n]*t1) @ w2 + b2)
__global__ void k_gcfused(const float4* __restrict__ xin4, const float* __restrict__ csum,
                          const float* __restrict__ inv, const int* __restrict__ roff,
                          const int* __restrict__ col,
                          const float* __restrict__ w1, const float* __restrict__ b1,
                          const float* __restrict__ w2, const float* __restrict__ b2,
                          float4* __restrict__ xout4) {
    int r = blockIdx.x * blockDim.x + threadIdx.x;
    if (r >= N_ * C_) return;
    int n = r / C_, c = r - n * C_;
    float iv = inv[n];
    float xs[H_];
    const float4* sp = xin4 + (size_t)r * 8;
    #pragma unroll
    for (int q = 0; q < 8; ++q) {
        float4 v = sp[q];
        xs[4 * q + 0] = v.x * iv; xs[4 * q + 1] = v.y * iv;
        xs[4 * q + 2] = v.z * iv; xs[4 * q + 3] = v.w * iv;
    }
    int p1 = roff[n + 1];
    for (int p = roff[n]; p < p1; ++p) {
        int s = col[p];
        float ivs = inv[s];
        const float4* np = xin4 + ((size_t)s * C_ + c) * 8;
        #pragma unroll
        for (int q = 0; q < 8; ++q) {
            float4 v = np[q];
            xs[4 * q + 0] = fmaf(v.x, ivs, xs[4 * q + 0]);
            xs[4 * q + 1] = fmaf(v.y, ivs, xs[4 * q + 1]);
            xs[4 * q + 2] = fmaf(v.z, ivs, xs[4 * q + 2]);
            xs[4 * q + 3] = fmaf(v.w, ivs, xs[4 * q + 3]);
        }
    }
    float t1[H_];
    #pragma unroll
    for (int h = 0; h < H_; ++h) t1[h] = 0.0f;
    const float2* c2 = (const float2*)(csum + (size_t)r * CFGF);
    for (int kc = 0; kc < CFGF / 2; ++kc) {
        float2 cv = c2[kc];
        float cs[2] = {cv.x, cv.y};
        #pragma unroll
        for (int j = 0; j < 2; ++j) {
            int k = kc * 2 + j;
            #pragma unroll
            for (int h = 0; h < H_; ++h) t1[h] = fmaf(cs[j], w1[k * H_ + h], t1[h]);
        }
    }
    #pragma unroll
    for (int k = 0; k < H_; ++k) {
        float v = xs[k];
        #pragma unroll
        for (int h = 0; h < H_; ++h) t1[h] = fmaf(v, w1[(CFGF + k) * H_ + h], t1[h]);
    }
    float h1[H_];
    #pragma unroll
    for (int h = 0; h < H_; ++h) h1[h] = lrelu(fmaf(iv, t1[h], b1[h]));
    float acc[H_];
    #pragma unroll
    for (int h = 0; h < H_; ++h) acc[h] = b2[h];
    #pragma unroll
    for (int k = 0; k < H_; ++k) {
        float v = h1[k];
        #pragma unroll
        for (int h = 0; h < H_; ++h) acc[h] = fmaf(v, w2[k * H_ + h], acc[h]);
    }
    float4* o = xout4 + (size_t)r * 8;
    #pragma unroll
    for (int q = 0; q < 8; ++q) {
        float4 v = sp[q];   // reload self row (L1/L2-hot) for the residual
        v.x += lrelu(acc[4 * q + 0]); v.y += lrelu(acc[4 * q + 1]);
        v.z += lrelu(acc[4 * q + 2]); v.w += lrelu(acc[4 * q + 3]);
        o[q] = v;
    }
}

// op_sum: 512 blocks x 256 thr; 6 node-slots x 40 float4-lanes; private LDS per slot
__global__ void k_opsum(const float4* __restrict__ xf4, const float4* __restrict__ xb4,
                        const int* __restrict__ sel, const int* __restrict__ gid,
                        float* __restrict__ osum, float* __restrict__ cnt) {
    __shared__ float4 ls[6 * G_ * 40];
    __shared__ float lc[6 * G_];
    for (int i = threadIdx.x; i < 6 * G_ * 40; i += blockDim.x) ls[i] = make_float4(0.f, 0.f, 0.f, 0.f);
    if (threadIdx.x < 6 * G_) lc[threadIdx.x] = 0.0f;
    __syncthreads();
    int j4 = threadIdx.x % 40, i = threadIdx.x / 40;
    const int NPB = CDIV(N_, 512);
    int start = blockIdx.x * NPB;
    int end = min(start + NPB, N_);
    if (i < 6) {
        for (int n = start + i; n < end; n += 6) {
            int g = gid[n];
            const float4* xr = sel[n] ? xb4 : xf4;
            float4 v = xr[(size_t)n * 40 + j4];
            int o = (i * G_ + g) * 40 + j4;
            float4 c = ls[o];
            c.x += v.x; c.y += v.y; c.z += v.z; c.w += v.w;
            ls[o] = c;
            if (j4 == 0) lc[i * G_ + g] += 1.0f;
        }
    }
    __syncthreads();
    for (int idx = threadIdx.x; idx < G_ * 40; idx += blockDim.x) {
        float4 s = ls[idx];
        #pragma unroll
        for (int q = 1; q < 6; ++q) {
            float4 v = ls[q * G_ * 40 + idx];
            s.x += v.x; s.y += v.y; s.z += v.z; s.w += v.w;
        }
        int g = idx / 40, j = idx - g * 40;
        float* o = osum + (size_t)g * XROW + j * 4;
        atomicAdd(o + 0, s.x); atomicAdd(o + 1, s.y);
        atomicAdd(o + 2, s.z); atomicAdd(o + 3, s.w);
    }
    if (threadIdx.x < G_) {
        float c = 0.0f;
        #pragma unroll
        for (int q = 0; q < 6; ++q) c += lc[q * G_ + threadIdx.x];
        atomicAdd(&cnt[threadIdx.x], c);
    }
}

// cfg_sum: 64 blocks x 256 thr
__global__ void k_cfgsum(const float4* __restrict__ xf4, const float4* __restrict__ xb4,
                         const int* __restrict__ sel, const int* __restrict__ csrc,
                         const int* __restrict__ cdst, const int* __restrict__ cfg_gid,
                         float* __restrict__ gsum) {
    __shared__ float4 ls[6 * G_ * 40];
    for (int i = threadIdx.x; i < 6 * G_ * 40; i += blockDim.x) ls[i] = make_float4(0.f, 0.f, 0.f, 0.f);
    __syncthreads();
    int j4 = threadIdx.x % 40, i = threadIdx.x / 40;
    const int EPB = CDIV(NC_, 64);
    int start = blockIdx.x * EPB;
    int end = min(start + EPB, NC_);
    if (i < 6) {
        for (int e = start + i; e < end; e += 6) {
            int g = cfg_gid[csrc[e]];
            int n = cdst[e];
            const float4* xr = sel[n] ? xb4 : xf4;
            float4 v = xr[(size_t)n * 40 + j4];
            int o = (i * G_ + g) * 40 + j4;
            float4 c = ls[o];
            c.x += v.x; c.y += v.y; c.z += v.z; c.w += v.w;
            ls[o] = c;
        }
    }
    __syncthreads();
    for (int idx = threadIdx.x; idx < G_ * 40; idx += blockDim.x) {
        float4 s = ls[idx];
        #pragma unroll
        for (int q = 1; q < 6; ++q) {
            float4 v = ls[q * G_ * 40 + idx];
            s.x += v.x; s.y += v.y; s.z += v.z; s.w += v.w;
        }
        int g = idx / 40, j = idx - g * 40;
        float* o = gsum + (size_t)g * XROW + j * 4;
        atomicAdd(o + 0, s.x); atomicAdd(o + 1, s.y);
        atomicAdd(o + 2, s.z); atomicAdd(o + 3, s.w);
    }
}

__global__ void k_final(const float* __restrict__ osum, const float* __restrict__ gsum,
                        const float* __restrict__ cnt, const float* __restrict__ pw1,
                        const float* __restrict__ pw2, float* __restrict__ out) {
    __shared__ float sw1[3 * H_ * H_];
    __shared__ float sw2[H_];
    for (int i = threadIdx.x; i < 3 * H_ * H_; i += blockDim.x) sw1[i] = pw1[i];
    if (threadIdx.x < H_) sw2[threadIdx.x] = pw2[threadIdx.x];
    __syncthreads();
    int t = threadIdx.x;
    if (t >= G_ * C_) return;
    int g = t / C_;
    const float* os = osum + (size_t)t * H_;
    const float* cs = gsum + (size_t)t * H_;
    float icnt = 1.0f / cnt[g];
    float a0[H_], a1[H_], a2[H_];
    float s1 = 0.0f, s2 = 0.0f;
    #pragma unroll
    for (int h = 0; h < H_; ++h) {
        float v1 = os[h], v2 = cs[h];
        a0[h] = v1 * icnt;
        a1[h] = v1; s1 = fmaf(v1, v1, s1);
        a2[h] = v2; s2 = fmaf(v2, v2, s2);
    }
    float r1 = 1.0f / sqrtf(fmaxf(s1, 1e-12f));
    float r2 = 1.0f / sqrtf(fmaxf(s2, 1e-12f));
    #pragma unroll
    for (int h = 0; h < H_; ++h) { a1[h] *= r1; a2[h] *= r2; }
    float o = 0.0f;
    #pragma unroll
    for (int h = 0; h < H_; ++h) {
        float a = 0.0f;
        #pragma unroll
        for (int k = 0; k < H_; ++k) a = fmaf(a0[k], sw1[k * H_ + h], a);
        #pragma unroll
        for (int k = 0; k < H_; ++k) a = fmaf(a1[k], sw1[(H_ + k) * H_ + h], a);
        #pragma unroll
        for (int k = 0; k < H_; ++k) a = fmaf(a2[k], sw1[(2 * H_ + k) * H_ + h], a);
        o = fmaf(lrelu(a), sw2[h], o);
    }
    out[t] = o;
}

extern "C" void kernel_launch(void* const* d_in, const int* in_sizes, int n_in,
                              void* d_out, int out_size, void* d_ws, size_t ws_size,
                              hipStream_t stream) {
    const float* op_feats     = (const float*)d_in[0];
    const float* config_feats = (const float*)d_in[1];
    const int*   op_ids       = (const int*)d_in[2];
    const int*   selected     = (const int*)d_in[3];
    const int*   feed_src     = (const int*)d_in[4];
    const int*   feed_dst     = (const int*)d_in[5];
    const int*   sfeed_src    = (const int*)d_in[6];
    const int*   sfeed_dst    = (const int*)d_in[7];
    const int*   config_src   = (const int*)d_in[8];
    const int*   config_dst   = (const int*)d_in[9];
    const int*   sconfig_src  = (const int*)d_in[10];
    const int*   sconfig_dst  = (const int*)d_in[11];
    const int*   op_gid       = (const int*)d_in[12];
    const int*   cfg_gid      = (const int*)d_in[13];
    const float* emb          = (const float*)d_in[14];
    const float* pre_w1       = (const float*)d_in[15];
    const float* pre_b1       = (const float*)d_in[16];
    const float* pre_w2       = (const float*)d_in[17];
    const float* pre_b2       = (const float*)d_in[18];
    const float* gc_w1[2]     = {(const float*)d_in[19], (const float*)d_in[23]};
    const float* gc_b1[2]     = {(const float*)d_in[20], (const float*)d_in[24]};
    const float* gc_w2[2]     = {(const float*)d_in[21], (const float*)d_in[25]};
    const float* gc_b2[2]     = {(const float*)d_in[22], (const float*)d_in[26]};
    const float* post_w1      = (const float*)d_in[27];
    const float* post_w2      = (const float*)d_in[28];

    char* ws = (char*)d_ws;
    size_t off = 0;
    auto alloc = [&](size_t bytes) { void* p = ws + off; off += (bytes + 255) & ~(size_t)255; return p; };
    float* nfw  = (float*)alloc((size_t)N_ * H_ * 4);
    float* nfwop= (float*)alloc((size_t)NUMOPS * H_ * 4);
    float* cfg  = (float*)alloc((size_t)N_ * CROW * 4);
    float* inv  = (float*)alloc((size_t)N_ * 4);
    int*   deg  = (int*)alloc((size_t)N_ * 4);
    float* xf   = (float*)alloc((size_t)N_ * XROW * 4);
    float* xb   = (float*)alloc((size_t)N_ * XROW * 4);
    float* csum = (float*)alloc((size_t)N_ * CROW * 4);
    float* xscr = (float*)alloc((size_t)N_ * XROW * 4);
    int*   roff = (int*)alloc((size_t)(N_ + 1) * 4);
    int*   cur  = (int*)alloc((size_t)N_ * 4);
    int*   aux  = (int*)alloc((size_t)512 * 4);
    int*   col  = (int*)alloc((size_t)2 * 160000 * 4);
    float* osum = (float*)alloc((size_t)G_ * XROW * 4);
    float* gsum = (float*)alloc((size_t)G_ * XROW * 4);
    float* cntb = (float*)alloc((size_t)G_ * 4);

    const int NB1 = CDIV(N_, 256);

    k_nfwop<<<CDIV(NUMOPS * H_, 256), 256, 0, stream>>>(emb, pre_w1, pre_b1, nfwop);
    k_nfw<<<CDIV(N_, 256), 256, 0, stream>>>(op_feats, op_ids, nfwop, pre_w1, nfw);

    for (int fwd = 0; fwd < 2; ++fwd) {
        const int* esrc = fwd ? sfeed_src : feed_src;
        const int* edst = fwd ? sfeed_dst : feed_dst;
        int Ecur = fwd ? in_sizes[6] : in_sizes[4];
        const int* csrc = fwd ? sconfig_src : config_src;
        const int* cdst = fwd ? sconfig_dst : config_dst;
        float* x0 = fwd ? xb : xf;   // pre output + final result buffer for this pass

        hipMemsetAsync(cfg, 0, (size_t)N_ * CROW * 4, stream);
        hipMemsetAsync(deg, 0, (size_t)N_ * 4, stream);
        k_cfg_scatter<<<CDIV(NC_ * CROW, 256), 256, 0, stream>>>(config_feats, csrc, cdst, cfg);
        k_deg<<<CDIV(Ecur, 256), 256, 0, stream>>>(esrc, edst, Ecur, deg);
        k_inv<<<CDIV(N_, 256), 256, 0, stream>>>(deg, inv);
        k_scan1<<<NB1, 256, 0, stream>>>(deg, roff, aux);
        k_scan2<<<1, 512, 0, stream>>>(aux, NB1);
        k_scan3<<<CDIV(N_, 256), 256, 0, stream>>>(roff, aux, cur, 2 * Ecur);
        k_fill<<<CDIV(Ecur, 256), 256, 0, stream>>>(esrc, edst, Ecur, cur, col);

        k_csum_gather<<<CDIV(N_ * 45, 256), 256, 0, stream>>>((const float2*)cfg, inv, roff, col,
                                                              (float2*)csum);
        k_pre<<<CDIV(N_ * C_, 256), 256, 0, stream>>>(cfg, nfw, pre_w1, pre_w2, pre_b2, x0);

        // layer 0: x0 -> xscr ; layer 1: xscr -> x0
        k_gcfused<<<CDIV(N_ * C_, 256), 256, 0, stream>>>((const float4*)x0, csum, inv, roff, col,
                                                          gc_w1[0], gc_b1[0], gc_w2[0], gc_b2[0],
                                                          (float4*)xscr);
        k_gcfused<<<CDIV(N_ * C_, 256), 256, 0, stream>>>((const float4*)xscr, csum, inv, roff, col,
                                                          gc_w1[1], gc_b1[1], gc_w2[1], gc_b2[1],
                                                          (float4*)x0);
    }

    hipMemsetAsync(osum, 0, (size_t)G_ * XROW * 4, stream);
    hipMemsetAsync(gsum, 0, (size_t)G_ * XROW * 4, stream);
    hipMemsetAsync(cntb, 0, (size_t)G_ * 4, stream);
    k_opsum<<<512, 256, 0, stream>>>((const float4*)xf, (const float4*)xb, selected, op_gid, osum, cntb);
    k_cfgsum<<<64, 256, 0, stream>>>((const float4*)xf, (const float4*)xb, selected,
                                     config_src, config_dst, cfg_gid, gsum);
    k_final<<<1, 128, 0, stream>>>(osum, gsum, cntb, post_w1, post_w2, (float*)d_out);
}